// Round 8
// baseline (302.019 us; speedup 1.0000x reference)
//
#include <hip/hip_runtime.h>
#include <type_traits>

constexpr int N_N  = 20000;
constexpr int N_E  = 320000;
constexpr int N_ET = N_E + N_N;   // 340000 (self-loops appended)
constexpr int IN_D = 128;
constexpr int HID  = 256;
constexpr int H1   = 4;           // heads layer 1
constexpr int OUTD = 128;
constexpr float SLOPE = 0.2f;
constexpr float BNEPS = 1e-5f;

typedef unsigned short u16;
typedef float f32x4 __attribute__((ext_vector_type(4)));
typedef short bf16x8 __attribute__((ext_vector_type(8)));

__device__ __forceinline__ float bf2f(u16 u) { return __uint_as_float((unsigned)u << 16); }
__device__ __forceinline__ u16 f2bf(float f) {
  unsigned u = __float_as_uint(f);
  unsigned r = u + 0x7FFFu + ((u >> 16) & 1u);  // RNE
  return (u16)(r >> 16);
}

// ---------------- prep: W1/W2 bf16 transpose-pack + degree histogram ----------------
__global__ __launch_bounds__(256) void prep_k(const int* __restrict__ ei,
                                              const float* __restrict__ W1,
                                              const float* __restrict__ W2,
                                              u16* __restrict__ wp1,
                                              u16* __restrict__ wp2,
                                              int* __restrict__ cnt) {
  const int i = blockIdx.x * 256 + threadIdx.x;
  if (i < IN_D * HID) {           // 32768
    const int n = i >> 7, k = i & 127;
    wp1[i] = f2bf(W1[(size_t)k * HID + n]);
  }
  if (i < HID * OUTD) {           // 32768
    const int n = i >> 8, k = i & 255;
    wp2[i] = f2bf(W2[(size_t)k * OUTD + n]);
  }
  if (i < N_ET) {
    const int dst = (i < N_E) ? ei[N_E + i] : (i - N_E);
    atomicAdd(&cnt[dst], 1);
  }
}

// ---------------- scan: 1 block, 1024 thr, shuffle wave-scan (2 barriers) ----------
__global__ __launch_bounds__(1024) void scan_k(const int* __restrict__ cnt,
                                               int* __restrict__ rowptr,
                                               int* __restrict__ wcur) {
  __shared__ int wsum[17];
  const int tid = threadIdx.x, lane = tid & 63, wv = tid >> 6;
  constexpr int CHK = 20;         // 1024*20 = 20480 >= 20000
  const int base = tid * CHK;
  int c[CHK];
  int s = 0;
#pragma unroll
  for (int j = 0; j < CHK; ++j) {
    const int idx = base + j;
    c[j] = (idx < N_N) ? cnt[idx] : 0;
    s += c[j];
  }
  const int own = s;
#pragma unroll
  for (int off = 1; off < 64; off <<= 1) {
    const int v = __shfl_up(s, off, 64);
    if (lane >= off) s += v;
  }
  if (lane == 63) wsum[wv] = s;
  __syncthreads();
  if (tid == 0) {
    int run = 0;
#pragma unroll
    for (int i = 0; i < 16; ++i) { const int t = wsum[i]; wsum[i] = run; run += t; }
    wsum[16] = run;
  }
  __syncthreads();
  int run = wsum[wv] + (s - own);
#pragma unroll
  for (int j = 0; j < CHK; ++j) {
    const int idx = base + j;
    if (idx < N_N) {
      rowptr[idx] = run;
      wcur[idx]   = run;
      run += c[j];
    }
  }
  if (tid == 0) rowptr[N_N] = wsum[16];
}

// ---------------- fused: CSR scatter (blocks >= GB1) + GEMM1 MFMA + alpha1 --------
constexpr int GB1 = N_N / 16;   // 1250 gemm blocks
__global__ __launch_bounds__(256) void sg_k(const float* __restrict__ x,
                                            const u16* __restrict__ wp,     // [256][128]
                                            const float* __restrict__ asrc,
                                            const float* __restrict__ adst,
                                            u16* __restrict__ h,            // [20000][256]
                                            float* __restrict__ as_,        // [20000][4]
                                            float* __restrict__ ad_,
                                            const int* __restrict__ ei,
                                            int* __restrict__ wcur,
                                            int* __restrict__ col) {
  const int tid = threadIdx.x;
  if (blockIdx.x >= GB1) {
    const int i = (blockIdx.x - GB1) * 256 + tid;
    if (i >= N_ET) return;
    int s, dst;
    if (i < N_E) { s = ei[i]; dst = ei[N_E + i]; } else { s = dst = i - N_E; }
    const int pos = atomicAdd(&wcur[dst], 1);
    col[pos] = s;
    return;
  }
  const int wv = tid >> 6, lane = tid & 63;
  const int q = lane >> 4, t = lane & 15;
  const int m0 = blockIdx.x * 16;
  const int n0 = wv * 64;
  f32x4 acc[4] = {};
#pragma unroll
  for (int kb = 0; kb < 4; ++kb) {
    const int k0 = kb * 32 + q * 8;
    const float4 x0 = *(const float4*)(x + (size_t)(m0 + t) * 128 + k0);
    const float4 x1 = *(const float4*)(x + (size_t)(m0 + t) * 128 + k0 + 4);
    bf16x8 a;
    a[0] = (short)f2bf(x0.x); a[1] = (short)f2bf(x0.y);
    a[2] = (short)f2bf(x0.z); a[3] = (short)f2bf(x0.w);
    a[4] = (short)f2bf(x1.x); a[5] = (short)f2bf(x1.y);
    a[6] = (short)f2bf(x1.z); a[7] = (short)f2bf(x1.w);
#pragma unroll
    for (int nt = 0; nt < 4; ++nt) {
      const int n = n0 + nt * 16 + t;
      const bf16x8 b = *(const bf16x8*)(wp + (size_t)n * 128 + k0);
      acc[nt] = __builtin_amdgcn_mfma_f32_16x16x32_bf16(a, b, acc[nt], 0, 0, 0);
    }
  }
  float ps[4] = {0.f, 0.f, 0.f, 0.f}, pd[4] = {0.f, 0.f, 0.f, 0.f};
#pragma unroll
  for (int nt = 0; nt < 4; ++nt) {
    const int coln = n0 + nt * 16 + t;
    const float a_s = asrc[coln], a_d = adst[coln];
#pragma unroll
    for (int r = 0; r < 4; ++r) {
      const float d = acc[nt][r];
      h[(size_t)(m0 + q * 4 + r) * 256 + coln] = f2bf(d);
      ps[r] += d * a_s;
      pd[r] += d * a_d;
    }
  }
#pragma unroll
  for (int off = 1; off < 16; off <<= 1)
#pragma unroll
    for (int r = 0; r < 4; ++r) {
      ps[r] += __shfl_xor(ps[r], off, 64);
      pd[r] += __shfl_xor(pd[r], off, 64);
    }
  if (t == 0) {
#pragma unroll
    for (int r = 0; r < 4; ++r) {
      const int row = m0 + q * 4 + r;
      as_[(size_t)row * 4 + wv] = ps[r];
      ad_[(size_t)row * 4 + wv] = pd[r];
    }
  }
}

// ---------------- agg layer 1: 2 independent half-waves per node (128 ch each) -----
// block = 4 waves = 2 nodes x 2 halves; waves fully independent (no barrier).
// Single-pass softmax (e bounded for this distribution => exp safe in fp32).
__global__ __launch_bounds__(256) void gat_agg1_k(const int* __restrict__ rowptr,
                                                  const int* __restrict__ col,
                                                  const u16* __restrict__ h,
                                                  const float* __restrict__ as_,
                                                  const float* __restrict__ ad_,
                                                  u16* __restrict__ out) {
  __shared__ int   s_s[4][64];
  __shared__ float s_w[4][64][2];
  const int tid = threadIdx.x;
  const int wv = tid >> 6, lane = tid & 63;
  const int nl = wv >> 1, half = wv & 1;
  const int n = blockIdx.x * 2 + nl;
  const int beg = rowptr[n], end = rowptr[n + 1];
  const int c0 = half * 128 + lane * 2;
  const int hl = lane >> 5;        // head-within-half for this lane
  const int hb = half * 2;         // this half-wave covers heads hb, hb+1
  const float adv0 = ad_[n * 4 + hb], adv1 = ad_[n * 4 + hb + 1];

  float a0 = 0.f, a1 = 0.f, smh = 0.f;

  for (int j0 = beg; j0 < end; j0 += 64) {
    const int cnt = min(64, end - j0);
    const int j = j0 + lane;
    const int sl = col[(j < end) ? j : beg];
    s_s[wv][lane] = sl;
    const float4 av = *(const float4*)(as_ + (size_t)sl * 4);
    const float* ap = (const float*)&av;
    float e0 = ap[hb] + adv0;     e0 = e0 > 0.f ? e0 : SLOPE * e0;
    float e1 = ap[hb + 1] + adv1; e1 = e1 > 0.f ? e1 : SLOPE * e1;
    s_w[wv][lane][0] = (j < end) ? __expf(e0) : 0.f;
    s_w[wv][lane][1] = (j < end) ? __expf(e1) : 0.f;
    // wave-synchronous LDS (same wave wrote it)

    int jj = 0;
    for (; jj + 8 <= cnt; jj += 8) {
      int sv[8]; float wt[8]; ushort2 g[8];
#pragma unroll
      for (int u = 0; u < 8; ++u) {
        sv[u] = s_s[wv][jj + u];
        wt[u] = s_w[wv][jj + u][hl];
      }
#pragma unroll
      for (int u = 0; u < 8; ++u) g[u] = *(const ushort2*)(h + (size_t)sv[u] * 256 + c0);
#pragma unroll
      for (int u = 0; u < 8; ++u) {
        smh += wt[u];
        a0 = fmaf(wt[u], bf2f(g[u].x), a0);
        a1 = fmaf(wt[u], bf2f(g[u].y), a1);
      }
    }
    for (; jj < cnt; ++jj) {
      const int s = s_s[wv][jj];
      const float w = s_w[wv][jj][hl];
      const ushort2 g = *(const ushort2*)(h + (size_t)s * 256 + c0);
      smh += w;
      a0 = fmaf(w, bf2f(g.x), a0);
      a1 = fmaf(w, bf2f(g.y), a1);
    }
  }

  const float r = 1.f / (smh + 1e-16f);
  ushort2 o; o.x = f2bf(a0 * r); o.y = f2bf(a1 * r);
  *(ushort2*)(out + (size_t)n * 256 + c0) = o;
}

// ---------------- agg layer 2: 1 wave per node (2 ch/lane), independent waves ------
__global__ __launch_bounds__(256) void gat_agg2_k(const int* __restrict__ rowptr,
                                                  const int* __restrict__ col,
                                                  const u16* __restrict__ h,
                                                  const float* __restrict__ as_,
                                                  const float* __restrict__ ad_,
                                                  u16* __restrict__ out) {
  __shared__ int   s_s[4][64];
  __shared__ float s_w[4][64];
  const int tid = threadIdx.x;
  const int wv = tid >> 6, lane = tid & 63;
  const int n = blockIdx.x * 4 + wv;
  const int beg = rowptr[n], end = rowptr[n + 1];
  const int c0 = lane * 2;
  const float adv = ad_[n];

  float a0 = 0.f, a1 = 0.f, smh = 0.f;

  for (int j0 = beg; j0 < end; j0 += 64) {
    const int cnt = min(64, end - j0);
    const int j = j0 + lane;
    const int sl = col[(j < end) ? j : beg];
    s_s[wv][lane] = sl;
    float e = as_[sl] + adv;
    e = e > 0.f ? e : SLOPE * e;
    s_w[wv][lane] = (j < end) ? __expf(e) : 0.f;

    int jj = 0;
    for (; jj + 8 <= cnt; jj += 8) {
      int sv[8]; float wt[8]; ushort2 g[8];
#pragma unroll
      for (int u = 0; u < 8; ++u) {
        sv[u] = s_s[wv][jj + u];
        wt[u] = s_w[wv][jj + u];
      }
#pragma unroll
      for (int u = 0; u < 8; ++u) g[u] = *(const ushort2*)(h + (size_t)sv[u] * 128 + c0);
#pragma unroll
      for (int u = 0; u < 8; ++u) {
        smh += wt[u];
        a0 = fmaf(wt[u], bf2f(g[u].x), a0);
        a1 = fmaf(wt[u], bf2f(g[u].y), a1);
      }
    }
    for (; jj < cnt; ++jj) {
      const int s = s_s[wv][jj];
      const float w = s_w[wv][jj];
      const ushort2 g = *(const ushort2*)(h + (size_t)s * 128 + c0);
      smh += w;
      a0 = fmaf(w, bf2f(g.x), a0);
      a1 = fmaf(w, bf2f(g.y), a1);
    }
  }

  const float r = 1.f / (smh + 1e-16f);
  ushort2 o; o.x = f2bf(a0 * r); o.y = f2bf(a1 * r);
  *(ushort2*)(out + (size_t)n * 128 + c0) = o;
}

// ---------- BN stats over bf16 input (atomic partials into acc[2*CH]) ----------
template<int CH>
__global__ __launch_bounds__(CH) void bn_stats_k(const u16* __restrict__ X,
                                                 float* __restrict__ acc, int n) {
  const int c = threadIdx.x;
  float s = 0.f, ss = 0.f;
  for (int r = blockIdx.x; r < n; r += gridDim.x) {
    const float v = bf2f(X[(size_t)r * CH + c]);
    s += v; ss += v * v;
  }
  atomicAdd(&acc[c], s);
  atomicAdd(&acc[CH + c], ss);
}

// ---------------- GEMM2 (MFMA) + inline BN1 finalize + BN1/ELU on A + alpha2 ----
__global__ __launch_bounds__(256) void gemm2_mfma_k(const u16* __restrict__ hin,
                                                    const float* __restrict__ acc1, // [512] sums
                                                    const float* __restrict__ g1,
                                                    const float* __restrict__ b1,
                                                    const u16* __restrict__ wp,   // [128][256]
                                                    const float* __restrict__ asrc,
                                                    const float* __restrict__ adst,
                                                    u16* __restrict__ h2,
                                                    float* __restrict__ as_,
                                                    float* __restrict__ ad_) {
  __shared__ float scsh[512];
  __shared__ float red[2][32][2];
  const int tid = threadIdx.x;
  {  // inline bn_finalize1
    const float mean = acc1[tid] * (1.f / N_N);
    const float var  = acc1[256 + tid] * (1.f / N_N) - mean * mean;
    const float inv  = rsqrtf(var + BNEPS);
    const float sc   = g1[tid] * inv;
    scsh[tid]       = sc;
    scsh[256 + tid] = b1[tid] - mean * sc;
  }
  __syncthreads();
  const int wv = tid >> 6, lane = tid & 63;
  const int q = lane >> 4, t = lane & 15;
  const int mh = wv >> 1, nh = wv & 1;
  const int m0 = blockIdx.x * 32 + mh * 16;
  const int n0 = nh * 64;
  f32x4 acc[4] = {};
#pragma unroll
  for (int kb = 0; kb < 8; ++kb) {
    const int k0 = kb * 32 + q * 8;
    const ushort4 u0 = *(const ushort4*)(hin + (size_t)(m0 + t) * 256 + k0);
    const ushort4 u1 = *(const ushort4*)(hin + (size_t)(m0 + t) * 256 + k0 + 4);
    const float4 sc0 = *(const float4*)(scsh + k0);
    const float4 sc1 = *(const float4*)(scsh + k0 + 4);
    const float4 sh0 = *(const float4*)(scsh + 256 + k0);
    const float4 sh1 = *(const float4*)(scsh + 256 + k0 + 4);
    float v[8];
    v[0] = bf2f(u0.x) * sc0.x + sh0.x;
    v[1] = bf2f(u0.y) * sc0.y + sh0.y;
    v[2] = bf2f(u0.z) * sc0.z + sh0.z;
    v[3] = bf2f(u0.w) * sc0.w + sh0.w;
    v[4] = bf2f(u1.x) * sc1.x + sh1.x;
    v[5] = bf2f(u1.y) * sc1.y + sh1.y;
    v[6] = bf2f(u1.z) * sc1.z + sh1.z;
    v[7] = bf2f(u1.w) * sc1.w + sh1.w;
    bf16x8 a;
#pragma unroll
    for (int j = 0; j < 8; ++j) {
      const float e = v[j] > 0.f ? v[j] : __expf(v[j]) - 1.f;
      a[j] = (short)f2bf(e);
    }
#pragma unroll
    for (int nt = 0; nt < 4; ++nt) {
      const int n = n0 + nt * 16 + t;
      const bf16x8 b = *(const bf16x8*)(wp + (size_t)n * 256 + k0);
      acc[nt] = __builtin_amdgcn_mfma_f32_16x16x32_bf16(a, b, acc[nt], 0, 0, 0);
    }
  }
  float ps[4] = {0.f, 0.f, 0.f, 0.f}, pd[4] = {0.f, 0.f, 0.f, 0.f};
#pragma unroll
  for (int nt = 0; nt < 4; ++nt) {
    const int coln = n0 + nt * 16 + t;
    const float a_s = asrc[coln], a_d = adst[coln];
#pragma unroll
    for (int r = 0; r < 4; ++r) {
      const float d = acc[nt][r];
      h2[(size_t)(m0 + q * 4 + r) * 128 + coln] = f2bf(d);
      ps[r] += d * a_s;
      pd[r] += d * a_d;
    }
  }
#pragma unroll
  for (int off = 1; off < 16; off <<= 1)
#pragma unroll
    for (int r = 0; r < 4; ++r) {
      ps[r] += __shfl_xor(ps[r], off, 64);
      pd[r] += __shfl_xor(pd[r], off, 64);
    }
  if (t == 0) {
#pragma unroll
    for (int r = 0; r < 4; ++r) {
      red[0][mh * 16 + q * 4 + r][nh] = ps[r];
      red[1][mh * 16 + q * 4 + r][nh] = pd[r];
    }
  }
  __syncthreads();
  if (tid < 32) {
    as_[(size_t)blockIdx.x * 32 + tid] = red[0][tid][0] + red[0][tid][1];
    ad_[(size_t)blockIdx.x * 32 + tid] = red[1][tid][0] + red[1][tid][1];
  }
}

// ---------------- BN2 finalize + apply, bf16 -> fp32 out -------------
__global__ __launch_bounds__(256) void apply_k(const u16* __restrict__ X,
                                               const float* __restrict__ acc, // [256] sums
                                               const float* __restrict__ gamma,
                                               const float* __restrict__ beta,
                                               float* __restrict__ Y) {
  __shared__ float s_sc[128], s_sh[128];
  const int tid = threadIdx.x;
  if (tid < 128) {
    const float mean = acc[tid] * (1.f / N_N);
    const float var  = acc[128 + tid] * (1.f / N_N) - mean * mean;
    const float inv  = rsqrtf(var + BNEPS);
    const float sc   = gamma[tid] * inv;
    s_sc[tid] = sc;
    s_sh[tid] = beta[tid] - mean * sc;
  }
  __syncthreads();
  constexpr size_t TOT = (size_t)N_N * OUTD;
  for (size_t i = ((size_t)blockIdx.x * 256 + tid) * 4; i < TOT;
       i += (size_t)gridDim.x * 256 * 4) {
    const ushort4 u = *(const ushort4*)(X + i);
    const int c = (int)(i & 127);
    float4 o;
    o.x = bf2f(u.x) * s_sc[c]     + s_sh[c];
    o.y = bf2f(u.y) * s_sc[c + 1] + s_sh[c + 1];
    o.z = bf2f(u.z) * s_sc[c + 2] + s_sh[c + 2];
    o.w = bf2f(u.w) * s_sc[c + 3] + s_sh[c + 3];
    *(float4*)(Y + i) = o;
  }
}

// ---------------- workspace layout (4-byte element offsets) ----------------
constexpr size_t OFF_WP1  = 0;                                   // bf16 256*128
constexpr size_t OFF_WP2  = OFF_WP1  + (size_t)IN_D * HID / 2;
constexpr size_t OFF_H1   = OFF_WP2  + (size_t)HID * OUTD / 2;   // bf16 N_N*HID
constexpr size_t OFF_OUT1 = OFF_H1   + (size_t)N_N * HID / 2;
constexpr size_t OFF_H2   = OFF_OUT1 + (size_t)N_N * HID / 2;    // bf16 N_N*OUTD
constexpr size_t OFF_OUT2 = OFF_H2   + (size_t)N_N * OUTD / 2;
constexpr size_t OFF_AS1  = OFF_OUT2 + (size_t)N_N * OUTD / 2;   // fp32 N_N*4
constexpr size_t OFF_AD1  = OFF_AS1  + (size_t)N_N * H1;
constexpr size_t OFF_AS2  = OFF_AD1  + (size_t)N_N * H1;         // fp32 N_N
constexpr size_t OFF_AD2  = OFF_AS2  + (size_t)N_N;
constexpr size_t OFF_ROWP = OFF_AD2  + (size_t)N_N;              // int N_N+1
constexpr size_t OFF_COL  = OFF_ROWP + (size_t)(N_N + 1);        // int N_ET
constexpr size_t OFF_WCUR = OFF_COL  + (size_t)N_ET;             // int N_N
// zeroed region (one memset): cnt + acc1 + acc2
constexpr size_t OFF_CNT  = OFF_WCUR + (size_t)N_N;              // int N_N
constexpr size_t OFF_ACC1 = OFF_CNT  + (size_t)N_N;              // 512 fp32
constexpr size_t OFF_ACC2 = OFF_ACC1 + 512;                      // 256 fp32
constexpr size_t OFF_ZEND = OFF_ACC2 + 256;

extern "C" void kernel_launch(void* const* d_in, const int* in_sizes, int n_in,
                              void* d_out, int out_size, void* d_ws, size_t ws_size,
                              hipStream_t stream) {
  const float* x      = (const float*)d_in[0];
  const int*   ei     = (const int*)d_in[1];
  const float* W1     = (const float*)d_in[2];
  const float* asrc1  = (const float*)d_in[3];
  const float* adst1  = (const float*)d_in[4];
  // d_in[5] = bias1 (cancels under BN)
  const float* g1     = (const float*)d_in[6];
  const float* b1     = (const float*)d_in[7];
  const float* W2     = (const float*)d_in[8];
  const float* asrc2  = (const float*)d_in[9];
  const float* adst2  = (const float*)d_in[10];
  // d_in[11] = bias2 (cancels under BN)
  const float* g2     = (const float*)d_in[12];
  const float* b2     = (const float*)d_in[13];

  float* ws = (float*)d_ws;
  u16*   wp1   = (u16*)(ws + OFF_WP1);
  u16*   wp2   = (u16*)(ws + OFF_WP2);
  u16*   h1    = (u16*)(ws + OFF_H1);
  u16*   out1  = (u16*)(ws + OFF_OUT1);
  u16*   h2    = (u16*)(ws + OFF_H2);
  u16*   out2  = (u16*)(ws + OFF_OUT2);
  float* as1   = ws + OFF_AS1;
  float* ad1   = ws + OFF_AD1;
  float* as2   = ws + OFF_AS2;
  float* ad2   = ws + OFF_AD2;
  int*   rowp  = (int*)(ws + OFF_ROWP);
  int*   col   = (int*)(ws + OFF_COL);
  int*   wcur  = (int*)(ws + OFF_WCUR);
  int*   cnt   = (int*)(ws + OFF_CNT);
  float* acc1  = ws + OFF_ACC1;
  float* acc2  = ws + OFF_ACC2;
  float* outf  = (float*)d_out;

  // zero: cnt + acc1 + acc2 (contiguous, ~83 KB)
  hipMemsetAsync(cnt, 0, (OFF_ZEND - OFF_CNT) * sizeof(float), stream);

  const int eb = (N_ET + 255) / 256;   // 1329
  // 1. W packs + degree histogram
  prep_k<<<eb, 256, 0, stream>>>(ei, W1, W2, wp1, wp2, cnt);
  // 2. exclusive scan -> rowptr/wcur
  scan_k<<<1, 1024, 0, stream>>>(cnt, rowp, wcur);
  // 3. CSR scatter + GEMM1(+alpha1) fused
  sg_k<<<GB1 + eb, 256, 0, stream>>>(x, wp1, asrc1, adst1, h1, as1, ad1, ei, wcur, col);
  // 4. layer-1 edge softmax + aggregate (half-wave split, independent waves)
  gat_agg1_k<<<N_N / 2, 256, 0, stream>>>(rowp, col, h1, as1, ad1, out1);
  // 5. BN1 stats
  bn_stats_k<HID><<<512, HID, 0, stream>>>(out1, acc1, N_N);
  // 6. GEMM2 (BN1 finalize + BN1/ELU on A, fused alpha2)
  gemm2_mfma_k<<<N_N / 32, 256, 0, stream>>>(out1, acc1, g1, b1, wp2, asrc2, adst2, h2, as2, ad2);
  // 7. layer-2 edge softmax + aggregate
  gat_agg2_k<<<N_N / 4, 256, 0, stream>>>(rowp, col, h2, as2, ad2, out2);
  // 8. BN2 stats
  bn_stats_k<OUTD><<<512, OUTD, 0, stream>>>(out2, acc2, N_N);
  // 9. BN2 finalize + apply -> fp32 output
  apply_k<<<512, 256, 0, stream>>>(out2, acc2, g2, b2, outf);
}

// Round 9
// 262.531 us; speedup vs baseline: 1.1504x; 1.1504x over previous
//
#include <hip/hip_runtime.h>
#include <type_traits>

constexpr int N_N  = 20000;
constexpr int N_E  = 320000;
constexpr int N_ET = N_E + N_N;   // 340000 (self-loops appended)
constexpr int IN_D = 128;
constexpr int HID  = 256;
constexpr int H1   = 4;           // heads layer 1
constexpr int OUTD = 128;
constexpr float SLOPE = 0.2f;
constexpr float BNEPS = 1e-5f;
constexpr int NPART = 64;         // BN partial buffers (atomic-contention limiter)

typedef unsigned short u16;
typedef float f32x4 __attribute__((ext_vector_type(4)));
typedef short bf16x8 __attribute__((ext_vector_type(8)));

__device__ __forceinline__ float bf2f(u16 u) { return __uint_as_float((unsigned)u << 16); }
__device__ __forceinline__ u16 f2bf(float f) {
  unsigned u = __float_as_uint(f);
  unsigned r = u + 0x7FFFu + ((u >> 16) & 1u);  // RNE
  return (u16)(r >> 16);
}

// ---------------- prep: W1/W2 bf16 transpose-pack + degree histogram ----------------
__global__ __launch_bounds__(256) void prep_k(const int* __restrict__ ei,
                                              const float* __restrict__ W1,
                                              const float* __restrict__ W2,
                                              u16* __restrict__ wp1,
                                              u16* __restrict__ wp2,
                                              int* __restrict__ cnt) {
  const int i = blockIdx.x * 256 + threadIdx.x;
  if (i < IN_D * HID) {           // 32768
    const int n = i >> 7, k = i & 127;
    wp1[i] = f2bf(W1[(size_t)k * HID + n]);
  }
  if (i < HID * OUTD) {           // 32768
    const int n = i >> 8, k = i & 255;
    wp2[i] = f2bf(W2[(size_t)k * OUTD + n]);
  }
  if (i < N_ET) {
    const int dst = (i < N_E) ? ei[N_E + i] : (i - N_E);
    atomicAdd(&cnt[dst], 1);
  }
}

// ---------------- scan: 1 block, 1024 thr, shuffle wave-scan (2 barriers) ----------
__global__ __launch_bounds__(1024) void scan_k(const int* __restrict__ cnt,
                                               int* __restrict__ rowptr,
                                               int* __restrict__ wcur) {
  __shared__ int wsum[17];
  const int tid = threadIdx.x, lane = tid & 63, wv = tid >> 6;
  constexpr int CHK = 20;         // 1024*20 = 20480 >= 20000
  const int base = tid * CHK;
  int c[CHK];
  int s = 0;
#pragma unroll
  for (int j = 0; j < CHK; ++j) {
    const int idx = base + j;
    c[j] = (idx < N_N) ? cnt[idx] : 0;
    s += c[j];
  }
  const int own = s;
#pragma unroll
  for (int off = 1; off < 64; off <<= 1) {
    const int v = __shfl_up(s, off, 64);
    if (lane >= off) s += v;
  }
  if (lane == 63) wsum[wv] = s;
  __syncthreads();
  if (tid == 0) {
    int run = 0;
#pragma unroll
    for (int i = 0; i < 16; ++i) { const int t = wsum[i]; wsum[i] = run; run += t; }
    wsum[16] = run;
  }
  __syncthreads();
  int run = wsum[wv] + (s - own);
#pragma unroll
  for (int j = 0; j < CHK; ++j) {
    const int idx = base + j;
    if (idx < N_N) {
      rowptr[idx] = run;
      wcur[idx]   = run;
      run += c[j];
    }
  }
  if (tid == 0) rowptr[N_N] = wsum[16];
}

// ---------------- fused: CSR scatter (blocks >= GB1) + GEMM1 MFMA + alpha1 --------
constexpr int GB1 = N_N / 16;   // 1250 gemm blocks
__global__ __launch_bounds__(256) void sg_k(const float* __restrict__ x,
                                            const u16* __restrict__ wp,     // [256][128]
                                            const float* __restrict__ asrc,
                                            const float* __restrict__ adst,
                                            u16* __restrict__ h,            // [20000][256]
                                            float* __restrict__ as_,        // [20000][4]
                                            float* __restrict__ ad_,
                                            const int* __restrict__ ei,
                                            int* __restrict__ wcur,
                                            int* __restrict__ col) {
  const int tid = threadIdx.x;
  if (blockIdx.x >= GB1) {
    const int i = (blockIdx.x - GB1) * 256 + tid;
    if (i >= N_ET) return;
    int s, dst;
    if (i < N_E) { s = ei[i]; dst = ei[N_E + i]; } else { s = dst = i - N_E; }
    const int pos = atomicAdd(&wcur[dst], 1);
    col[pos] = s;
    return;
  }
  const int wv = tid >> 6, lane = tid & 63;
  const int q = lane >> 4, t = lane & 15;
  const int m0 = blockIdx.x * 16;
  const int n0 = wv * 64;
  f32x4 acc[4] = {};
#pragma unroll
  for (int kb = 0; kb < 4; ++kb) {
    const int k0 = kb * 32 + q * 8;
    const float4 x0 = *(const float4*)(x + (size_t)(m0 + t) * 128 + k0);
    const float4 x1 = *(const float4*)(x + (size_t)(m0 + t) * 128 + k0 + 4);
    bf16x8 a;
    a[0] = (short)f2bf(x0.x); a[1] = (short)f2bf(x0.y);
    a[2] = (short)f2bf(x0.z); a[3] = (short)f2bf(x0.w);
    a[4] = (short)f2bf(x1.x); a[5] = (short)f2bf(x1.y);
    a[6] = (short)f2bf(x1.z); a[7] = (short)f2bf(x1.w);
#pragma unroll
    for (int nt = 0; nt < 4; ++nt) {
      const int n = n0 + nt * 16 + t;
      const bf16x8 b = *(const bf16x8*)(wp + (size_t)n * 128 + k0);
      acc[nt] = __builtin_amdgcn_mfma_f32_16x16x32_bf16(a, b, acc[nt], 0, 0, 0);
    }
  }
  float ps[4] = {0.f, 0.f, 0.f, 0.f}, pd[4] = {0.f, 0.f, 0.f, 0.f};
#pragma unroll
  for (int nt = 0; nt < 4; ++nt) {
    const int coln = n0 + nt * 16 + t;
    const float a_s = asrc[coln], a_d = adst[coln];
#pragma unroll
    for (int r = 0; r < 4; ++r) {
      const float d = acc[nt][r];
      h[(size_t)(m0 + q * 4 + r) * 256 + coln] = f2bf(d);
      ps[r] += d * a_s;
      pd[r] += d * a_d;
    }
  }
#pragma unroll
  for (int off = 1; off < 16; off <<= 1)
#pragma unroll
    for (int r = 0; r < 4; ++r) {
      ps[r] += __shfl_xor(ps[r], off, 64);
      pd[r] += __shfl_xor(pd[r], off, 64);
    }
  if (t == 0) {
#pragma unroll
    for (int r = 0; r < 4; ++r) {
      const int row = m0 + q * 4 + r;
      as_[(size_t)row * 4 + wv] = ps[r];
      ad_[(size_t)row * 4 + wv] = pd[r];
    }
  }
}

// ---------------- agg layer 1: 2 half-waves per node (128 ch each) + BN stats ------
// block = 4 waves = 2 nodes x 2 halves. Single-pass softmax (e bounded, exp safe).
__global__ __launch_bounds__(256) void gat_agg1_k(const int* __restrict__ rowptr,
                                                  const int* __restrict__ col,
                                                  const u16* __restrict__ h,
                                                  const float* __restrict__ as_,
                                                  const float* __restrict__ ad_,
                                                  u16* __restrict__ out,
                                                  float* __restrict__ accp) {  // [NPART][512]
  __shared__ int   s_s[4][64];
  __shared__ float s_w[4][64][2];
  __shared__ float st_s[2][258], st_q[2][258];   // +2 pad: break pow-2 bank pattern
  const int tid = threadIdx.x;
  const int wv = tid >> 6, lane = tid & 63;
  const int nl = wv >> 1, half = wv & 1;
  const int n = blockIdx.x * 2 + nl;
  const int beg = rowptr[n], end = rowptr[n + 1];
  const int c0 = half * 128 + lane * 2;
  const int hl = lane >> 5;        // head-within-half for this lane
  const int hb = half * 2;         // this half-wave covers heads hb, hb+1
  const float adv0 = ad_[n * 4 + hb], adv1 = ad_[n * 4 + hb + 1];

  float a0 = 0.f, a1 = 0.f, smh = 0.f;

  for (int j0 = beg; j0 < end; j0 += 64) {
    const int cnt = min(64, end - j0);
    const int j = j0 + lane;
    const int sl = col[(j < end) ? j : beg];
    s_s[wv][lane] = sl;
    const float4 av = *(const float4*)(as_ + (size_t)sl * 4);
    const float* ap = (const float*)&av;
    float e0 = ap[hb] + adv0;     e0 = e0 > 0.f ? e0 : SLOPE * e0;
    float e1 = ap[hb + 1] + adv1; e1 = e1 > 0.f ? e1 : SLOPE * e1;
    s_w[wv][lane][0] = (j < end) ? __expf(e0) : 0.f;
    s_w[wv][lane][1] = (j < end) ? __expf(e1) : 0.f;
    // wave-synchronous LDS (same wave wrote it)

    int jj = 0;
    for (; jj + 8 <= cnt; jj += 8) {
      int sv[8]; float wt[8]; ushort2 g[8];
#pragma unroll
      for (int u = 0; u < 8; ++u) {
        sv[u] = s_s[wv][jj + u];
        wt[u] = s_w[wv][jj + u][hl];
      }
#pragma unroll
      for (int u = 0; u < 8; ++u) g[u] = *(const ushort2*)(h + (size_t)sv[u] * 256 + c0);
#pragma unroll
      for (int u = 0; u < 8; ++u) {
        smh += wt[u];
        a0 = fmaf(wt[u], bf2f(g[u].x), a0);
        a1 = fmaf(wt[u], bf2f(g[u].y), a1);
      }
    }
    for (; jj < cnt; ++jj) {
      const int s = s_s[wv][jj];
      const float w = s_w[wv][jj][hl];
      const ushort2 g = *(const ushort2*)(h + (size_t)s * 256 + c0);
      smh += w;
      a0 = fmaf(w, bf2f(g.x), a0);
      a1 = fmaf(w, bf2f(g.y), a1);
    }
  }

  const float r = 1.f / (smh + 1e-16f);
  const float v0 = a0 * r, v1 = a1 * r;
  ushort2 o; o.x = f2bf(v0); o.y = f2bf(v1);
  *(ushort2*)(out + (size_t)n * 256 + c0) = o;

  // BN1 stats: per-block reduce over 2 nodes, one atomic set per block
  st_s[nl][c0] = v0;      st_s[nl][c0 + 1] = v1;
  st_q[nl][c0] = v0 * v0; st_q[nl][c0 + 1] = v1 * v1;
  __syncthreads();
  {
    const int c = tid;   // 256 channels
    const float s = st_s[0][c] + st_s[1][c];
    const float q = st_q[0][c] + st_q[1][c];
    float* dst = accp + (size_t)(blockIdx.x & (NPART - 1)) * 512;
    atomicAdd(&dst[c], s);
    atomicAdd(&dst[256 + c], q);
  }
}

// ---------------- agg layer 2: 1 wave per node (V=2) + BN stats ----------------
__global__ __launch_bounds__(256) void gat_agg2_k(const int* __restrict__ rowptr,
                                                  const int* __restrict__ col,
                                                  const u16* __restrict__ h,
                                                  const float* __restrict__ as_,
                                                  const float* __restrict__ ad_,
                                                  u16* __restrict__ out,
                                                  float* __restrict__ accp) {  // [NPART][256]
  __shared__ int   s_s[4][64];
  __shared__ float s_w[4][64];
  __shared__ float st_s[4][130], st_q[4][130];   // +2 pad
  const int tid = threadIdx.x;
  const int wv = tid >> 6, lane = tid & 63;
  const int n = blockIdx.x * 4 + wv;
  const int beg = rowptr[n], end = rowptr[n + 1];
  const int c0 = lane * 2;
  const float adv = ad_[n];

  float a0 = 0.f, a1 = 0.f, smh = 0.f;

  for (int j0 = beg; j0 < end; j0 += 64) {
    const int cnt = min(64, end - j0);
    const int j = j0 + lane;
    const int sl = col[(j < end) ? j : beg];
    s_s[wv][lane] = sl;
    float e = as_[sl] + adv;
    e = e > 0.f ? e : SLOPE * e;
    s_w[wv][lane] = (j < end) ? __expf(e) : 0.f;

    int jj = 0;
    for (; jj + 8 <= cnt; jj += 8) {
      int sv[8]; float wt[8]; ushort2 g[8];
#pragma unroll
      for (int u = 0; u < 8; ++u) {
        sv[u] = s_s[wv][jj + u];
        wt[u] = s_w[wv][jj + u];
      }
#pragma unroll
      for (int u = 0; u < 8; ++u) g[u] = *(const ushort2*)(h + (size_t)sv[u] * 128 + c0);
#pragma unroll
      for (int u = 0; u < 8; ++u) {
        smh += wt[u];
        a0 = fmaf(wt[u], bf2f(g[u].x), a0);
        a1 = fmaf(wt[u], bf2f(g[u].y), a1);
      }
    }
    for (; jj < cnt; ++jj) {
      const int s = s_s[wv][jj];
      const float w = s_w[wv][jj];
      const ushort2 g = *(const ushort2*)(h + (size_t)s * 128 + c0);
      smh += w;
      a0 = fmaf(w, bf2f(g.x), a0);
      a1 = fmaf(w, bf2f(g.y), a1);
    }
  }

  const float r = 1.f / (smh + 1e-16f);
  const float v0 = a0 * r, v1 = a1 * r;
  ushort2 o; o.x = f2bf(v0); o.y = f2bf(v1);
  *(ushort2*)(out + (size_t)n * 128 + c0) = o;

  st_s[wv][c0] = v0;      st_s[wv][c0 + 1] = v1;
  st_q[wv][c0] = v0 * v0; st_q[wv][c0 + 1] = v1 * v1;
  __syncthreads();
  if (tid < 128) {
    const int c = tid;
    const float s = st_s[0][c] + st_s[1][c] + st_s[2][c] + st_s[3][c];
    const float q = st_q[0][c] + st_q[1][c] + st_q[2][c] + st_q[3][c];
    float* dst = accp + (size_t)(blockIdx.x & (NPART - 1)) * 256;
    atomicAdd(&dst[c], s);
    atomicAdd(&dst[128 + c], q);
  }
}

// ---------------- GEMM2 (MFMA) + BN1 finalize-from-partials + ELU on A + alpha2 ----
__global__ __launch_bounds__(256) void gemm2_mfma_k(const u16* __restrict__ hin,
                                                    const float* __restrict__ accp, // [NPART][512]
                                                    const float* __restrict__ g1,
                                                    const float* __restrict__ b1,
                                                    const u16* __restrict__ wp,   // [128][256]
                                                    const float* __restrict__ asrc,
                                                    const float* __restrict__ adst,
                                                    u16* __restrict__ h2,
                                                    float* __restrict__ as_,
                                                    float* __restrict__ ad_) {
  __shared__ float scsh[512];
  __shared__ float red[2][32][2];
  const int tid = threadIdx.x;
  {  // BN1 finalize: sum NPART partials per channel
    float s = 0.f, q = 0.f;
#pragma unroll
    for (int p = 0; p < NPART; ++p) {
      s += accp[(size_t)p * 512 + tid];
      q += accp[(size_t)p * 512 + 256 + tid];
    }
    const float mean = s * (1.f / N_N);
    const float var  = q * (1.f / N_N) - mean * mean;
    const float inv  = rsqrtf(var + BNEPS);
    const float sc   = g1[tid] * inv;
    scsh[tid]       = sc;
    scsh[256 + tid] = b1[tid] - mean * sc;
  }
  __syncthreads();
  const int wv = tid >> 6, lane = tid & 63;
  const int q = lane >> 4, t = lane & 15;
  const int mh = wv >> 1, nh = wv & 1;
  const int m0 = blockIdx.x * 32 + mh * 16;
  const int n0 = nh * 64;
  f32x4 acc[4] = {};
#pragma unroll
  for (int kb = 0; kb < 8; ++kb) {
    const int k0 = kb * 32 + q * 8;
    const ushort4 u0 = *(const ushort4*)(hin + (size_t)(m0 + t) * 256 + k0);
    const ushort4 u1 = *(const ushort4*)(hin + (size_t)(m0 + t) * 256 + k0 + 4);
    const float4 sc0 = *(const float4*)(scsh + k0);
    const float4 sc1 = *(const float4*)(scsh + k0 + 4);
    const float4 sh0 = *(const float4*)(scsh + 256 + k0);
    const float4 sh1 = *(const float4*)(scsh + 256 + k0 + 4);
    float v[8];
    v[0] = bf2f(u0.x) * sc0.x + sh0.x;
    v[1] = bf2f(u0.y) * sc0.y + sh0.y;
    v[2] = bf2f(u0.z) * sc0.z + sh0.z;
    v[3] = bf2f(u0.w) * sc0.w + sh0.w;
    v[4] = bf2f(u1.x) * sc1.x + sh1.x;
    v[5] = bf2f(u1.y) * sc1.y + sh1.y;
    v[6] = bf2f(u1.z) * sc1.z + sh1.z;
    v[7] = bf2f(u1.w) * sc1.w + sh1.w;
    bf16x8 a;
#pragma unroll
    for (int j = 0; j < 8; ++j) {
      const float e = v[j] > 0.f ? v[j] : __expf(v[j]) - 1.f;
      a[j] = (short)f2bf(e);
    }
#pragma unroll
    for (int nt = 0; nt < 4; ++nt) {
      const int n = n0 + nt * 16 + t;
      const bf16x8 b = *(const bf16x8*)(wp + (size_t)n * 256 + k0);
      acc[nt] = __builtin_amdgcn_mfma_f32_16x16x32_bf16(a, b, acc[nt], 0, 0, 0);
    }
  }
  float ps[4] = {0.f, 0.f, 0.f, 0.f}, pd[4] = {0.f, 0.f, 0.f, 0.f};
#pragma unroll
  for (int nt = 0; nt < 4; ++nt) {
    const int coln = n0 + nt * 16 + t;
    const float a_s = asrc[coln], a_d = adst[coln];
#pragma unroll
    for (int r = 0; r < 4; ++r) {
      const float d = acc[nt][r];
      h2[(size_t)(m0 + q * 4 + r) * 128 + coln] = f2bf(d);
      ps[r] += d * a_s;
      pd[r] += d * a_d;
    }
  }
#pragma unroll
  for (int off = 1; off < 16; off <<= 1)
#pragma unroll
    for (int r = 0; r < 4; ++r) {
      ps[r] += __shfl_xor(ps[r], off, 64);
      pd[r] += __shfl_xor(pd[r], off, 64);
    }
  if (t == 0) {
#pragma unroll
    for (int r = 0; r < 4; ++r) {
      red[0][mh * 16 + q * 4 + r][nh] = ps[r];
      red[1][mh * 16 + q * 4 + r][nh] = pd[r];
    }
  }
  __syncthreads();
  if (tid < 32) {
    as_[(size_t)blockIdx.x * 32 + tid] = red[0][tid][0] + red[0][tid][1];
    ad_[(size_t)blockIdx.x * 32 + tid] = red[1][tid][0] + red[1][tid][1];
  }
}

// ---------------- BN2 finalize-from-partials + apply, bf16 -> fp32 out -------------
__global__ __launch_bounds__(256) void apply_k(const u16* __restrict__ X,
                                               const float* __restrict__ accp, // [NPART][256]
                                               const float* __restrict__ gamma,
                                               const float* __restrict__ beta,
                                               float* __restrict__ Y) {
  __shared__ float s_sc[128], s_sh[128];
  const int tid = threadIdx.x;
  if (tid < 128) {
    float s = 0.f, q = 0.f;
#pragma unroll
    for (int p = 0; p < NPART; ++p) {
      s += accp[(size_t)p * 256 + tid];
      q += accp[(size_t)p * 256 + 128 + tid];
    }
    const float mean = s * (1.f / N_N);
    const float var  = q * (1.f / N_N) - mean * mean;
    const float inv  = rsqrtf(var + BNEPS);
    const float sc   = gamma[tid] * inv;
    s_sc[tid] = sc;
    s_sh[tid] = beta[tid] - mean * sc;
  }
  __syncthreads();
  constexpr size_t TOT = (size_t)N_N * OUTD;
  for (size_t i = ((size_t)blockIdx.x * 256 + tid) * 4; i < TOT;
       i += (size_t)gridDim.x * 256 * 4) {
    const ushort4 u = *(const ushort4*)(X + i);
    const int c = (int)(i & 127);
    float4 o;
    o.x = bf2f(u.x) * s_sc[c]     + s_sh[c];
    o.y = bf2f(u.y) * s_sc[c + 1] + s_sh[c + 1];
    o.z = bf2f(u.z) * s_sc[c + 2] + s_sh[c + 2];
    o.w = bf2f(u.w) * s_sc[c + 3] + s_sh[c + 3];
    *(float4*)(Y + i) = o;
  }
}

// ---------------- workspace layout (4-byte element offsets) ----------------
constexpr size_t OFF_WP1  = 0;                                   // bf16 256*128
constexpr size_t OFF_WP2  = OFF_WP1  + (size_t)IN_D * HID / 2;
constexpr size_t OFF_H1   = OFF_WP2  + (size_t)HID * OUTD / 2;   // bf16 N_N*HID
constexpr size_t OFF_OUT1 = OFF_H1   + (size_t)N_N * HID / 2;
constexpr size_t OFF_H2   = OFF_OUT1 + (size_t)N_N * HID / 2;    // bf16 N_N*OUTD
constexpr size_t OFF_OUT2 = OFF_H2   + (size_t)N_N * OUTD / 2;
constexpr size_t OFF_AS1  = OFF_OUT2 + (size_t)N_N * OUTD / 2;   // fp32 N_N*4
constexpr size_t OFF_AD1  = OFF_AS1  + (size_t)N_N * H1;
constexpr size_t OFF_AS2  = OFF_AD1  + (size_t)N_N * H1;         // fp32 N_N
constexpr size_t OFF_AD2  = OFF_AS2  + (size_t)N_N;
constexpr size_t OFF_ROWP = OFF_AD2  + (size_t)N_N;              // int N_N+1
constexpr size_t OFF_COL  = OFF_ROWP + (size_t)(N_N + 1);        // int N_ET
constexpr size_t OFF_WCUR = OFF_COL  + (size_t)N_ET;             // int N_N
// zeroed region (one memset): cnt + acc partials
constexpr size_t OFF_CNT  = OFF_WCUR + (size_t)N_N;              // int N_N
constexpr size_t OFF_ACC1 = OFF_CNT  + (size_t)N_N;              // NPART*512 fp32
constexpr size_t OFF_ACC2 = OFF_ACC1 + (size_t)NPART * 512;      // NPART*256 fp32
constexpr size_t OFF_ZEND = OFF_ACC2 + (size_t)NPART * 256;

extern "C" void kernel_launch(void* const* d_in, const int* in_sizes, int n_in,
                              void* d_out, int out_size, void* d_ws, size_t ws_size,
                              hipStream_t stream) {
  const float* x      = (const float*)d_in[0];
  const int*   ei     = (const int*)d_in[1];
  const float* W1     = (const float*)d_in[2];
  const float* asrc1  = (const float*)d_in[3];
  const float* adst1  = (const float*)d_in[4];
  // d_in[5] = bias1 (cancels under BN)
  const float* g1     = (const float*)d_in[6];
  const float* b1     = (const float*)d_in[7];
  const float* W2     = (const float*)d_in[8];
  const float* asrc2  = (const float*)d_in[9];
  const float* adst2  = (const float*)d_in[10];
  // d_in[11] = bias2 (cancels under BN)
  const float* g2     = (const float*)d_in[12];
  const float* b2     = (const float*)d_in[13];

  float* ws = (float*)d_ws;
  u16*   wp1   = (u16*)(ws + OFF_WP1);
  u16*   wp2   = (u16*)(ws + OFF_WP2);
  u16*   h1    = (u16*)(ws + OFF_H1);
  u16*   out1  = (u16*)(ws + OFF_OUT1);
  u16*   h2    = (u16*)(ws + OFF_H2);
  u16*   out2  = (u16*)(ws + OFF_OUT2);
  float* as1   = ws + OFF_AS1;
  float* ad1   = ws + OFF_AD1;
  float* as2   = ws + OFF_AS2;
  float* ad2   = ws + OFF_AD2;
  int*   rowp  = (int*)(ws + OFF_ROWP);
  int*   col   = (int*)(ws + OFF_COL);
  int*   wcur  = (int*)(ws + OFF_WCUR);
  int*   cnt   = (int*)(ws + OFF_CNT);
  float* acc1p = ws + OFF_ACC1;
  float* acc2p = ws + OFF_ACC2;
  float* outf  = (float*)d_out;

  // zero: cnt + acc partials (contiguous, ~272 KB)
  hipMemsetAsync(cnt, 0, (OFF_ZEND - OFF_CNT) * sizeof(float), stream);

  const int eb = (N_ET + 255) / 256;   // 1329
  // 1. W packs + degree histogram
  prep_k<<<eb, 256, 0, stream>>>(ei, W1, W2, wp1, wp2, cnt);
  // 2. exclusive scan -> rowptr/wcur
  scan_k<<<1, 1024, 0, stream>>>(cnt, rowp, wcur);
  // 3. CSR scatter + GEMM1(+alpha1) fused
  sg_k<<<GB1 + eb, 256, 0, stream>>>(x, wp1, asrc1, adst1, h1, as1, ad1, ei, wcur, col);
  // 4. layer-1 edge softmax + aggregate + BN1 stats partials
  gat_agg1_k<<<N_N / 2, 256, 0, stream>>>(rowp, col, h1, as1, ad1, out1, acc1p);
  // 5. GEMM2 (BN1 finalize + BN1/ELU on A, fused alpha2)
  gemm2_mfma_k<<<N_N / 32, 256, 0, stream>>>(out1, acc1p, g1, b1, wp2, asrc2, adst2, h2, as2, ad2);
  // 6. layer-2 edge softmax + aggregate + BN2 stats partials
  gat_agg2_k<<<N_N / 4, 256, 0, stream>>>(rowp, col, h2, as2, ad2, out2, acc2p);
  // 7. BN2 finalize + apply -> fp32 output
  apply_k<<<512, 256, 0, stream>>>(out2, acc2p, g2, b2, outf);
}

// Round 10
// 250.835 us; speedup vs baseline: 1.2041x; 1.0466x over previous
//
#include <hip/hip_runtime.h>
#include <type_traits>

constexpr int N_N  = 20000;
constexpr int N_E  = 320000;
constexpr int N_ET = N_E + N_N;   // 340000 (self-loops appended)
constexpr int IN_D = 128;
constexpr int HID  = 256;
constexpr int H1   = 4;           // heads layer 1
constexpr int OUTD = 128;
constexpr float SLOPE = 0.2f;
constexpr float BNEPS = 1e-5f;
constexpr int NPART = 32;         // BN partial buffers (atomic-contention limiter)

typedef unsigned short u16;
typedef float f32x4 __attribute__((ext_vector_type(4)));
typedef short bf16x8 __attribute__((ext_vector_type(8)));

__device__ __forceinline__ float bf2f(u16 u) { return __uint_as_float((unsigned)u << 16); }
__device__ __forceinline__ u16 f2bf(float f) {
  unsigned u = __float_as_uint(f);
  unsigned r = u + 0x7FFFu + ((u >> 16) & 1u);  // RNE
  return (u16)(r >> 16);
}

// ---------------- prep: W1/W2 bf16 transpose-pack + degree histogram ----------------
__global__ __launch_bounds__(256) void prep_k(const int* __restrict__ ei,
                                              const float* __restrict__ W1,
                                              const float* __restrict__ W2,
                                              u16* __restrict__ wp1,
                                              u16* __restrict__ wp2,
                                              int* __restrict__ cnt) {
  const int i = blockIdx.x * 256 + threadIdx.x;
  if (i < IN_D * HID) {           // 32768
    const int n = i >> 7, k = i & 127;
    wp1[i] = f2bf(W1[(size_t)k * HID + n]);
  }
  if (i < HID * OUTD) {           // 32768
    const int n = i >> 8, k = i & 255;
    wp2[i] = f2bf(W2[(size_t)k * OUTD + n]);
  }
  if (i < N_ET) {
    const int dst = (i < N_E) ? ei[N_E + i] : (i - N_E);
    atomicAdd(&cnt[dst], 1);
  }
}

// ---------------- scan: 1 block, 1024 thr, shuffle wave-scan (2 barriers) ----------
__global__ __launch_bounds__(1024) void scan_k(const int* __restrict__ cnt,
                                               int* __restrict__ rowptr,
                                               int* __restrict__ wcur) {
  __shared__ int wsum[17];
  const int tid = threadIdx.x, lane = tid & 63, wv = tid >> 6;
  constexpr int CHK = 20;         // 1024*20 = 20480 >= 20000
  const int base = tid * CHK;
  int c[CHK];
  int s = 0;
#pragma unroll
  for (int j = 0; j < CHK; ++j) {
    const int idx = base + j;
    c[j] = (idx < N_N) ? cnt[idx] : 0;
    s += c[j];
  }
  const int own = s;
#pragma unroll
  for (int off = 1; off < 64; off <<= 1) {
    const int v = __shfl_up(s, off, 64);
    if (lane >= off) s += v;
  }
  if (lane == 63) wsum[wv] = s;
  __syncthreads();
  if (tid == 0) {
    int run = 0;
#pragma unroll
    for (int i = 0; i < 16; ++i) { const int t = wsum[i]; wsum[i] = run; run += t; }
    wsum[16] = run;
  }
  __syncthreads();
  int run = wsum[wv] + (s - own);
#pragma unroll
  for (int j = 0; j < CHK; ++j) {
    const int idx = base + j;
    if (idx < N_N) {
      rowptr[idx] = run;
      wcur[idx]   = run;
      run += c[j];
    }
  }
  if (tid == 0) rowptr[N_N] = wsum[16];
}

// ---------------- fused: CSR scatter (blocks >= GB1) + GEMM1 MFMA + alpha1 --------
constexpr int GB1 = N_N / 16;   // 1250 gemm blocks
__global__ __launch_bounds__(256) void sg_k(const float* __restrict__ x,
                                            const u16* __restrict__ wp,     // [256][128]
                                            const float* __restrict__ asrc,
                                            const float* __restrict__ adst,
                                            u16* __restrict__ h,            // [20000][256]
                                            float* __restrict__ as_,        // [20000][4]
                                            float* __restrict__ ad_,
                                            const int* __restrict__ ei,
                                            int* __restrict__ wcur,
                                            int* __restrict__ col) {
  const int tid = threadIdx.x;
  if (blockIdx.x >= GB1) {
    const int i = (blockIdx.x - GB1) * 256 + tid;
    if (i >= N_ET) return;
    int s, dst;
    if (i < N_E) { s = ei[i]; dst = ei[N_E + i]; } else { s = dst = i - N_E; }
    const int pos = atomicAdd(&wcur[dst], 1);
    col[pos] = s;
    return;
  }
  const int wv = tid >> 6, lane = tid & 63;
  const int q = lane >> 4, t = lane & 15;
  const int m0 = blockIdx.x * 16;
  const int n0 = wv * 64;
  f32x4 acc[4] = {};
#pragma unroll
  for (int kb = 0; kb < 4; ++kb) {
    const int k0 = kb * 32 + q * 8;
    const float4 x0 = *(const float4*)(x + (size_t)(m0 + t) * 128 + k0);
    const float4 x1 = *(const float4*)(x + (size_t)(m0 + t) * 128 + k0 + 4);
    bf16x8 a;
    a[0] = (short)f2bf(x0.x); a[1] = (short)f2bf(x0.y);
    a[2] = (short)f2bf(x0.z); a[3] = (short)f2bf(x0.w);
    a[4] = (short)f2bf(x1.x); a[5] = (short)f2bf(x1.y);
    a[6] = (short)f2bf(x1.z); a[7] = (short)f2bf(x1.w);
#pragma unroll
    for (int nt = 0; nt < 4; ++nt) {
      const int n = n0 + nt * 16 + t;
      const bf16x8 b = *(const bf16x8*)(wp + (size_t)n * 128 + k0);
      acc[nt] = __builtin_amdgcn_mfma_f32_16x16x32_bf16(a, b, acc[nt], 0, 0, 0);
    }
  }
  float ps[4] = {0.f, 0.f, 0.f, 0.f}, pd[4] = {0.f, 0.f, 0.f, 0.f};
#pragma unroll
  for (int nt = 0; nt < 4; ++nt) {
    const int coln = n0 + nt * 16 + t;
    const float a_s = asrc[coln], a_d = adst[coln];
#pragma unroll
    for (int r = 0; r < 4; ++r) {
      const float d = acc[nt][r];
      h[(size_t)(m0 + q * 4 + r) * 256 + coln] = f2bf(d);
      ps[r] += d * a_s;
      pd[r] += d * a_d;
    }
  }
#pragma unroll
  for (int off = 1; off < 16; off <<= 1)
#pragma unroll
    for (int r = 0; r < 4; ++r) {
      ps[r] += __shfl_xor(ps[r], off, 64);
      pd[r] += __shfl_xor(pd[r], off, 64);
    }
  if (t == 0) {
#pragma unroll
    for (int r = 0; r < 4; ++r) {
      const int row = m0 + q * 4 + r;
      as_[(size_t)row * 4 + wv] = ps[r];
      ad_[(size_t)row * 4 + wv] = pd[r];
    }
  }
}

// ---------------- agg layer 1: 2 half-waves per node (128 ch each) + BN stats ------
// block = 4 waves = 2 nodes x 2 halves. Single-pass softmax (e bounded, exp safe).
// 16-deep gather unroll: a mean-degree-17 node's edges nearly all in flight at once.
__global__ __launch_bounds__(256) void gat_agg1_k(const int* __restrict__ rowptr,
                                                  const int* __restrict__ col,
                                                  const u16* __restrict__ h,
                                                  const float* __restrict__ as_,
                                                  const float* __restrict__ ad_,
                                                  u16* __restrict__ out,
                                                  float* __restrict__ accp) {  // [NPART][512]
  __shared__ int   s_s[4][64];
  __shared__ float s_w[4][64][2];
  __shared__ float st_s[2][256], st_q[2][256];
  const int tid = threadIdx.x;
  const int wv = tid >> 6, lane = tid & 63;
  const int nl = wv >> 1, half = wv & 1;
  const int n = blockIdx.x * 2 + nl;
  const int beg = rowptr[n], end = rowptr[n + 1];
  const int c0 = half * 128 + lane * 2;
  const int hl = lane >> 5;        // head-within-half for this lane
  const int hb = half * 2;         // this half-wave covers heads hb, hb+1
  const float adv0 = ad_[n * 4 + hb], adv1 = ad_[n * 4 + hb + 1];

  float a0 = 0.f, a1 = 0.f, smh = 0.f;

  for (int j0 = beg; j0 < end; j0 += 64) {
    const int cnt = min(64, end - j0);
    const int j = j0 + lane;
    const int sl = col[(j < end) ? j : beg];
    s_s[wv][lane] = sl;
    const float4 av = *(const float4*)(as_ + (size_t)sl * 4);
    const float* ap = (const float*)&av;
    float e0 = ap[hb] + adv0;     e0 = e0 > 0.f ? e0 : SLOPE * e0;
    float e1 = ap[hb + 1] + adv1; e1 = e1 > 0.f ? e1 : SLOPE * e1;
    s_w[wv][lane][0] = (j < end) ? __expf(e0) : 0.f;
    s_w[wv][lane][1] = (j < end) ? __expf(e1) : 0.f;
    // wave-synchronous LDS (same wave wrote it)

    int jj = 0;
    for (; jj + 16 <= cnt; jj += 16) {
      int sv[16]; float wt[16]; ushort2 g[16];
#pragma unroll
      for (int u = 0; u < 16; ++u) {
        sv[u] = s_s[wv][jj + u];
        wt[u] = s_w[wv][jj + u][hl];
      }
#pragma unroll
      for (int u = 0; u < 16; ++u) g[u] = *(const ushort2*)(h + (size_t)sv[u] * 256 + c0);
#pragma unroll
      for (int u = 0; u < 16; ++u) {
        smh += wt[u];
        a0 = fmaf(wt[u], bf2f(g[u].x), a0);
        a1 = fmaf(wt[u], bf2f(g[u].y), a1);
      }
    }
    for (; jj + 4 <= cnt; jj += 4) {
      int sv[4]; float wt[4]; ushort2 g[4];
#pragma unroll
      for (int u = 0; u < 4; ++u) {
        sv[u] = s_s[wv][jj + u];
        wt[u] = s_w[wv][jj + u][hl];
      }
#pragma unroll
      for (int u = 0; u < 4; ++u) g[u] = *(const ushort2*)(h + (size_t)sv[u] * 256 + c0);
#pragma unroll
      for (int u = 0; u < 4; ++u) {
        smh += wt[u];
        a0 = fmaf(wt[u], bf2f(g[u].x), a0);
        a1 = fmaf(wt[u], bf2f(g[u].y), a1);
      }
    }
    for (; jj < cnt; ++jj) {
      const int s = s_s[wv][jj];
      const float w = s_w[wv][jj][hl];
      const ushort2 g = *(const ushort2*)(h + (size_t)s * 256 + c0);
      smh += w;
      a0 = fmaf(w, bf2f(g.x), a0);
      a1 = fmaf(w, bf2f(g.y), a1);
    }
  }

  const float r = 1.f / (smh + 1e-16f);
  const float v0 = a0 * r, v1 = a1 * r;
  ushort2 o; o.x = f2bf(v0); o.y = f2bf(v1);
  *(ushort2*)(out + (size_t)n * 256 + c0) = o;

  // BN1 stats: per-block reduce over 2 nodes, one atomic set per block
  st_s[nl][c0] = v0;      st_s[nl][c0 + 1] = v1;
  st_q[nl][c0] = v0 * v0; st_q[nl][c0 + 1] = v1 * v1;
  __syncthreads();
  {
    const int c = tid;   // 256 channels
    const float s = st_s[0][c] + st_s[1][c];
    const float q = st_q[0][c] + st_q[1][c];
    float* dst = accp + (size_t)(blockIdx.x & (NPART - 1)) * 512;
    atomicAdd(&dst[c], s);
    atomicAdd(&dst[256 + c], q);
  }
}

// ---------------- agg layer 2: 1 wave per node (V=2) + BN stats ----------------
__global__ __launch_bounds__(256) void gat_agg2_k(const int* __restrict__ rowptr,
                                                  const int* __restrict__ col,
                                                  const u16* __restrict__ h,
                                                  const float* __restrict__ as_,
                                                  const float* __restrict__ ad_,
                                                  u16* __restrict__ out,
                                                  float* __restrict__ accp) {  // [NPART][256]
  __shared__ int   s_s[4][64];
  __shared__ float s_w[4][64];
  __shared__ float st_s[4][128], st_q[4][128];
  const int tid = threadIdx.x;
  const int wv = tid >> 6, lane = tid & 63;
  const int n = blockIdx.x * 4 + wv;
  const int beg = rowptr[n], end = rowptr[n + 1];
  const int c0 = lane * 2;
  const float adv = ad_[n];

  float a0 = 0.f, a1 = 0.f, smh = 0.f;

  for (int j0 = beg; j0 < end; j0 += 64) {
    const int cnt = min(64, end - j0);
    const int j = j0 + lane;
    const int sl = col[(j < end) ? j : beg];
    s_s[wv][lane] = sl;
    float e = as_[sl] + adv;
    e = e > 0.f ? e : SLOPE * e;
    s_w[wv][lane] = (j < end) ? __expf(e) : 0.f;

    int jj = 0;
    for (; jj + 16 <= cnt; jj += 16) {
      int sv[16]; float wt[16]; ushort2 g[16];
#pragma unroll
      for (int u = 0; u < 16; ++u) {
        sv[u] = s_s[wv][jj + u];
        wt[u] = s_w[wv][jj + u];
      }
#pragma unroll
      for (int u = 0; u < 16; ++u) g[u] = *(const ushort2*)(h + (size_t)sv[u] * 128 + c0);
#pragma unroll
      for (int u = 0; u < 16; ++u) {
        smh += wt[u];
        a0 = fmaf(wt[u], bf2f(g[u].x), a0);
        a1 = fmaf(wt[u], bf2f(g[u].y), a1);
      }
    }
    for (; jj + 4 <= cnt; jj += 4) {
      int sv[4]; float wt[4]; ushort2 g[4];
#pragma unroll
      for (int u = 0; u < 4; ++u) {
        sv[u] = s_s[wv][jj + u];
        wt[u] = s_w[wv][jj + u];
      }
#pragma unroll
      for (int u = 0; u < 4; ++u) g[u] = *(const ushort2*)(h + (size_t)sv[u] * 128 + c0);
#pragma unroll
      for (int u = 0; u < 4; ++u) {
        smh += wt[u];
        a0 = fmaf(wt[u], bf2f(g[u].x), a0);
        a1 = fmaf(wt[u], bf2f(g[u].y), a1);
      }
    }
    for (; jj < cnt; ++jj) {
      const int s = s_s[wv][jj];
      const float w = s_w[wv][jj];
      const ushort2 g = *(const ushort2*)(h + (size_t)s * 128 + c0);
      smh += w;
      a0 = fmaf(w, bf2f(g.x), a0);
      a1 = fmaf(w, bf2f(g.y), a1);
    }
  }

  const float r = 1.f / (smh + 1e-16f);
  const float v0 = a0 * r, v1 = a1 * r;
  ushort2 o; o.x = f2bf(v0); o.y = f2bf(v1);
  *(ushort2*)(out + (size_t)n * 128 + c0) = o;

  st_s[wv][c0] = v0;      st_s[wv][c0 + 1] = v1;
  st_q[wv][c0] = v0 * v0; st_q[wv][c0 + 1] = v1 * v1;
  __syncthreads();
  if (tid < 128) {
    const int c = tid;
    const float s = st_s[0][c] + st_s[1][c] + st_s[2][c] + st_s[3][c];
    const float q = st_q[0][c] + st_q[1][c] + st_q[2][c] + st_q[3][c];
    float* dst = accp + (size_t)(blockIdx.x & (NPART - 1)) * 256;
    atomicAdd(&dst[c], s);
    atomicAdd(&dst[128 + c], q);
  }
}

// ---------------- GEMM2 (MFMA) + BN1 finalize-from-partials + ELU on A + alpha2 ----
__global__ __launch_bounds__(256) void gemm2_mfma_k(const u16* __restrict__ hin,
                                                    const float* __restrict__ accp, // [NPART][512]
                                                    const float* __restrict__ g1,
                                                    const float* __restrict__ b1,
                                                    const u16* __restrict__ wp,   // [128][256]
                                                    const float* __restrict__ asrc,
                                                    const float* __restrict__ adst,
                                                    u16* __restrict__ h2,
                                                    float* __restrict__ as_,
                                                    float* __restrict__ ad_) {
  __shared__ float scsh[512];
  __shared__ float red[2][32][2];
  const int tid = threadIdx.x;
  {  // BN1 finalize: sum NPART partials per channel
    float s = 0.f, q = 0.f;
#pragma unroll
    for (int p = 0; p < NPART; ++p) {
      s += accp[(size_t)p * 512 + tid];
      q += accp[(size_t)p * 512 + 256 + tid];
    }
    const float mean = s * (1.f / N_N);
    const float var  = q * (1.f / N_N) - mean * mean;
    const float inv  = rsqrtf(var + BNEPS);
    const float sc   = g1[tid] * inv;
    scsh[tid]       = sc;
    scsh[256 + tid] = b1[tid] - mean * sc;
  }
  __syncthreads();
  const int wv = tid >> 6, lane = tid & 63;
  const int q = lane >> 4, t = lane & 15;
  const int mh = wv >> 1, nh = wv & 1;
  const int m0 = blockIdx.x * 32 + mh * 16;
  const int n0 = nh * 64;
  f32x4 acc[4] = {};
#pragma unroll
  for (int kb = 0; kb < 8; ++kb) {
    const int k0 = kb * 32 + q * 8;
    const ushort4 u0 = *(const ushort4*)(hin + (size_t)(m0 + t) * 256 + k0);
    const ushort4 u1 = *(const ushort4*)(hin + (size_t)(m0 + t) * 256 + k0 + 4);
    const float4 sc0 = *(const float4*)(scsh + k0);
    const float4 sc1 = *(const float4*)(scsh + k0 + 4);
    const float4 sh0 = *(const float4*)(scsh + 256 + k0);
    const float4 sh1 = *(const float4*)(scsh + 256 + k0 + 4);
    float v[8];
    v[0] = bf2f(u0.x) * sc0.x + sh0.x;
    v[1] = bf2f(u0.y) * sc0.y + sh0.y;
    v[2] = bf2f(u0.z) * sc0.z + sh0.z;
    v[3] = bf2f(u0.w) * sc0.w + sh0.w;
    v[4] = bf2f(u1.x) * sc1.x + sh1.x;
    v[5] = bf2f(u1.y) * sc1.y + sh1.y;
    v[6] = bf2f(u1.z) * sc1.z + sh1.z;
    v[7] = bf2f(u1.w) * sc1.w + sh1.w;
    bf16x8 a;
#pragma unroll
    for (int j = 0; j < 8; ++j) {
      const float e = v[j] > 0.f ? v[j] : __expf(v[j]) - 1.f;
      a[j] = (short)f2bf(e);
    }
#pragma unroll
    for (int nt = 0; nt < 4; ++nt) {
      const int n = n0 + nt * 16 + t;
      const bf16x8 b = *(const bf16x8*)(wp + (size_t)n * 256 + k0);
      acc[nt] = __builtin_amdgcn_mfma_f32_16x16x32_bf16(a, b, acc[nt], 0, 0, 0);
    }
  }
  float ps[4] = {0.f, 0.f, 0.f, 0.f}, pd[4] = {0.f, 0.f, 0.f, 0.f};
#pragma unroll
  for (int nt = 0; nt < 4; ++nt) {
    const int coln = n0 + nt * 16 + t;
    const float a_s = asrc[coln], a_d = adst[coln];
#pragma unroll
    for (int r = 0; r < 4; ++r) {
      const float d = acc[nt][r];
      h2[(size_t)(m0 + q * 4 + r) * 128 + coln] = f2bf(d);
      ps[r] += d * a_s;
      pd[r] += d * a_d;
    }
  }
#pragma unroll
  for (int off = 1; off < 16; off <<= 1)
#pragma unroll
    for (int r = 0; r < 4; ++r) {
      ps[r] += __shfl_xor(ps[r], off, 64);
      pd[r] += __shfl_xor(pd[r], off, 64);
    }
  if (t == 0) {
#pragma unroll
    for (int r = 0; r < 4; ++r) {
      red[0][mh * 16 + q * 4 + r][nh] = ps[r];
      red[1][mh * 16 + q * 4 + r][nh] = pd[r];
    }
  }
  __syncthreads();
  if (tid < 32) {
    as_[(size_t)blockIdx.x * 32 + tid] = red[0][tid][0] + red[0][tid][1];
    ad_[(size_t)blockIdx.x * 32 + tid] = red[1][tid][0] + red[1][tid][1];
  }
}

// ---------------- BN2 finalize-from-partials + apply, bf16 -> fp32 out -------------
__global__ __launch_bounds__(256) void apply_k(const u16* __restrict__ X,
                                               const float* __restrict__ accp, // [NPART][256]
                                               const float* __restrict__ gamma,
                                               const float* __restrict__ beta,
                                               float* __restrict__ Y) {
  __shared__ float s_sc[128], s_sh[128];
  const int tid = threadIdx.x;
  if (tid < 128) {
    float s = 0.f, q = 0.f;
#pragma unroll
    for (int p = 0; p < NPART; ++p) {
      s += accp[(size_t)p * 256 + tid];
      q += accp[(size_t)p * 256 + 128 + tid];
    }
    const float mean = s * (1.f / N_N);
    const float var  = q * (1.f / N_N) - mean * mean;
    const float inv  = rsqrtf(var + BNEPS);
    const float sc   = gamma[tid] * inv;
    s_sc[tid] = sc;
    s_sh[tid] = beta[tid] - mean * sc;
  }
  __syncthreads();
  constexpr size_t TOT = (size_t)N_N * OUTD;
  for (size_t i = ((size_t)blockIdx.x * 256 + tid) * 4; i < TOT;
       i += (size_t)gridDim.x * 256 * 4) {
    const ushort4 u = *(const ushort4*)(X + i);
    const int c = (int)(i & 127);
    float4 o;
    o.x = bf2f(u.x) * s_sc[c]     + s_sh[c];
    o.y = bf2f(u.y) * s_sc[c + 1] + s_sh[c + 1];
    o.z = bf2f(u.z) * s_sc[c + 2] + s_sh[c + 2];
    o.w = bf2f(u.w) * s_sc[c + 3] + s_sh[c + 3];
    *(float4*)(Y + i) = o;
  }
}

// ---------------- workspace layout (4-byte element offsets) ----------------
constexpr size_t OFF_WP1  = 0;                                   // bf16 256*128
constexpr size_t OFF_WP2  = OFF_WP1  + (size_t)IN_D * HID / 2;
constexpr size_t OFF_H1   = OFF_WP2  + (size_t)HID * OUTD / 2;   // bf16 N_N*HID
constexpr size_t OFF_OUT1 = OFF_H1   + (size_t)N_N * HID / 2;
constexpr size_t OFF_H2   = OFF_OUT1 + (size_t)N_N * HID / 2;    // bf16 N_N*OUTD
constexpr size_t OFF_OUT2 = OFF_H2   + (size_t)N_N * OUTD / 2;
constexpr size_t OFF_AS1  = OFF_OUT2 + (size_t)N_N * OUTD / 2;   // fp32 N_N*4
constexpr size_t OFF_AD1  = OFF_AS1  + (size_t)N_N * H1;
constexpr size_t OFF_AS2  = OFF_AD1  + (size_t)N_N * H1;         // fp32 N_N
constexpr size_t OFF_AD2  = OFF_AS2  + (size_t)N_N;
constexpr size_t OFF_ROWP = OFF_AD2  + (size_t)N_N;              // int N_N+1
constexpr size_t OFF_COL  = OFF_ROWP + (size_t)(N_N + 1);        // int N_ET
constexpr size_t OFF_WCUR = OFF_COL  + (size_t)N_ET;             // int N_N
// zeroed region (one memset): cnt + acc partials
constexpr size_t OFF_CNT  = OFF_WCUR + (size_t)N_N;              // int N_N
constexpr size_t OFF_ACC1 = OFF_CNT  + (size_t)N_N;              // NPART*512 fp32
constexpr size_t OFF_ACC2 = OFF_ACC1 + (size_t)NPART * 512;      // NPART*256 fp32
constexpr size_t OFF_ZEND = OFF_ACC2 + (size_t)NPART * 256;

extern "C" void kernel_launch(void* const* d_in, const int* in_sizes, int n_in,
                              void* d_out, int out_size, void* d_ws, size_t ws_size,
                              hipStream_t stream) {
  const float* x      = (const float*)d_in[0];
  const int*   ei     = (const int*)d_in[1];
  const float* W1     = (const float*)d_in[2];
  const float* asrc1  = (const float*)d_in[3];
  const float* adst1  = (const float*)d_in[4];
  // d_in[5] = bias1 (cancels under BN)
  const float* g1     = (const float*)d_in[6];
  const float* b1     = (const float*)d_in[7];
  const float* W2     = (const float*)d_in[8];
  const float* asrc2  = (const float*)d_in[9];
  const float* adst2  = (const float*)d_in[10];
  // d_in[11] = bias2 (cancels under BN)
  const float* g2     = (const float*)d_in[12];
  const float* b2     = (const float*)d_in[13];

  float* ws = (float*)d_ws;
  u16*   wp1   = (u16*)(ws + OFF_WP1);
  u16*   wp2   = (u16*)(ws + OFF_WP2);
  u16*   h1    = (u16*)(ws + OFF_H1);
  u16*   out1  = (u16*)(ws + OFF_OUT1);
  u16*   h2    = (u16*)(ws + OFF_H2);
  u16*   out2  = (u16*)(ws + OFF_OUT2);
  float* as1   = ws + OFF_AS1;
  float* ad1   = ws + OFF_AD1;
  float* as2   = ws + OFF_AS2;
  float* ad2   = ws + OFF_AD2;
  int*   rowp  = (int*)(ws + OFF_ROWP);
  int*   col   = (int*)(ws + OFF_COL);
  int*   wcur  = (int*)(ws + OFF_WCUR);
  int*   cnt   = (int*)(ws + OFF_CNT);
  float* acc1p = ws + OFF_ACC1;
  float* acc2p = ws + OFF_ACC2;
  float* outf  = (float*)d_out;

  // zero: cnt + acc partials (contiguous, ~178 KB)
  hipMemsetAsync(cnt, 0, (OFF_ZEND - OFF_CNT) * sizeof(float), stream);

  const int eb = (N_ET + 255) / 256;   // 1329
  // 1. W packs + degree histogram
  prep_k<<<eb, 256, 0, stream>>>(ei, W1, W2, wp1, wp2, cnt);
  // 2. exclusive scan -> rowptr/wcur
  scan_k<<<1, 1024, 0, stream>>>(cnt, rowp, wcur);
  // 3. CSR scatter + GEMM1(+alpha1) fused
  sg_k<<<GB1 + eb, 256, 0, stream>>>(x, wp1, asrc1, adst1, h1, as1, ad1, ei, wcur, col);
  // 4. layer-1 edge softmax + aggregate + BN1 stats partials
  gat_agg1_k<<<N_N / 2, 256, 0, stream>>>(rowp, col, h1, as1, ad1, out1, acc1p);
  // 5. GEMM2 (BN1 finalize + BN1/ELU on A, fused alpha2)
  gemm2_mfma_k<<<N_N / 32, 256, 0, stream>>>(out1, acc1p, g1, b1, wp2, asrc2, adst2, h2, as2, ad2);
  // 6. layer-2 edge softmax + aggregate + BN2 stats partials
  gat_agg2_k<<<N_N / 4, 256, 0, stream>>>(rowp, col, h2, as2, ad2, out2, acc2p);
  // 7. BN2 finalize + apply -> fp32 output
  apply_k<<<512, 256, 0, stream>>>(out2, acc2p, g2, b2, outf);
}

// Round 11
// 249.391 us; speedup vs baseline: 1.2110x; 1.0058x over previous
//
#include <hip/hip_runtime.h>
#include <type_traits>

constexpr int N_N  = 20000;
constexpr int N_E  = 320000;
constexpr int N_ET = N_E + N_N;   // 340000 (self-loops appended)
constexpr int IN_D = 128;
constexpr int HID  = 256;
constexpr int H1   = 4;           // heads layer 1
constexpr int OUTD = 128;
constexpr float SLOPE = 0.2f;
constexpr float BNEPS = 1e-5f;
constexpr int NPART1 = 64;        // BN1 partials: agg1 has 10000 blocks -> 156 RMW/addr
constexpr int NPART2 = 32;        // BN2 partials: agg2 has  5000 blocks -> 156 RMW/addr

typedef unsigned short u16;
typedef float f32x4 __attribute__((ext_vector_type(4)));
typedef short bf16x8 __attribute__((ext_vector_type(8)));

__device__ __forceinline__ float bf2f(u16 u) { return __uint_as_float((unsigned)u << 16); }
__device__ __forceinline__ u16 f2bf(float f) {
  unsigned u = __float_as_uint(f);
  unsigned r = u + 0x7FFFu + ((u >> 16) & 1u);  // RNE
  return (u16)(r >> 16);
}

// ---------------- prep: W1/W2 bf16 transpose-pack + degree histogram ----------------
__global__ __launch_bounds__(256) void prep_k(const int* __restrict__ ei,
                                              const float* __restrict__ W1,
                                              const float* __restrict__ W2,
                                              u16* __restrict__ wp1,
                                              u16* __restrict__ wp2,
                                              int* __restrict__ cnt) {
  const int i = blockIdx.x * 256 + threadIdx.x;
  if (i < IN_D * HID) {           // 32768
    const int n = i >> 7, k = i & 127;
    wp1[i] = f2bf(W1[(size_t)k * HID + n]);
  }
  if (i < HID * OUTD) {           // 32768
    const int n = i >> 8, k = i & 255;
    wp2[i] = f2bf(W2[(size_t)k * OUTD + n]);
  }
  if (i < N_ET) {
    const int dst = (i < N_E) ? ei[N_E + i] : (i - N_E);
    atomicAdd(&cnt[dst], 1);
  }
}

// ---------------- scan: 1 block, 1024 thr, shuffle wave-scan (2 barriers) ----------
__global__ __launch_bounds__(1024) void scan_k(const int* __restrict__ cnt,
                                               int* __restrict__ rowptr,
                                               int* __restrict__ wcur) {
  __shared__ int wsum[17];
  const int tid = threadIdx.x, lane = tid & 63, wv = tid >> 6;
  constexpr int CHK = 20;         // 1024*20 = 20480 >= 20000
  const int base = tid * CHK;
  int c[CHK];
  int s = 0;
#pragma unroll
  for (int j = 0; j < CHK; ++j) {
    const int idx = base + j;
    c[j] = (idx < N_N) ? cnt[idx] : 0;
    s += c[j];
  }
  const int own = s;
#pragma unroll
  for (int off = 1; off < 64; off <<= 1) {
    const int v = __shfl_up(s, off, 64);
    if (lane >= off) s += v;
  }
  if (lane == 63) wsum[wv] = s;
  __syncthreads();
  if (tid == 0) {
    int run = 0;
#pragma unroll
    for (int i = 0; i < 16; ++i) { const int t = wsum[i]; wsum[i] = run; run += t; }
    wsum[16] = run;
  }
  __syncthreads();
  int run = wsum[wv] + (s - own);
#pragma unroll
  for (int j = 0; j < CHK; ++j) {
    const int idx = base + j;
    if (idx < N_N) {
      rowptr[idx] = run;
      wcur[idx]   = run;
      run += c[j];
    }
  }
  if (tid == 0) rowptr[N_N] = wsum[16];
}

// ---------------- fused: CSR scatter (blocks >= GB1) + GEMM1 MFMA + alpha1 --------
constexpr int GB1 = N_N / 16;   // 1250 gemm blocks
__global__ __launch_bounds__(256) void sg_k(const float* __restrict__ x,
                                            const u16* __restrict__ wp,     // [256][128]
                                            const float* __restrict__ asrc,
                                            const float* __restrict__ adst,
                                            u16* __restrict__ h,            // [20000][256]
                                            float* __restrict__ as_,        // [20000][4]
                                            float* __restrict__ ad_,
                                            const int* __restrict__ ei,
                                            int* __restrict__ wcur,
                                            int* __restrict__ col) {
  const int tid = threadIdx.x;
  if (blockIdx.x >= GB1) {
    const int i = (blockIdx.x - GB1) * 256 + tid;
    if (i >= N_ET) return;
    int s, dst;
    if (i < N_E) { s = ei[i]; dst = ei[N_E + i]; } else { s = dst = i - N_E; }
    const int pos = atomicAdd(&wcur[dst], 1);
    col[pos] = s;
    return;
  }
  const int wv = tid >> 6, lane = tid & 63;
  const int q = lane >> 4, t = lane & 15;
  const int m0 = blockIdx.x * 16;
  const int n0 = wv * 64;
  f32x4 acc[4] = {};
#pragma unroll
  for (int kb = 0; kb < 4; ++kb) {
    const int k0 = kb * 32 + q * 8;
    const float4 x0 = *(const float4*)(x + (size_t)(m0 + t) * 128 + k0);
    const float4 x1 = *(const float4*)(x + (size_t)(m0 + t) * 128 + k0 + 4);
    bf16x8 a;
    a[0] = (short)f2bf(x0.x); a[1] = (short)f2bf(x0.y);
    a[2] = (short)f2bf(x0.z); a[3] = (short)f2bf(x0.w);
    a[4] = (short)f2bf(x1.x); a[5] = (short)f2bf(x1.y);
    a[6] = (short)f2bf(x1.z); a[7] = (short)f2bf(x1.w);
#pragma unroll
    for (int nt = 0; nt < 4; ++nt) {
      const int n = n0 + nt * 16 + t;
      const bf16x8 b = *(const bf16x8*)(wp + (size_t)n * 128 + k0);
      acc[nt] = __builtin_amdgcn_mfma_f32_16x16x32_bf16(a, b, acc[nt], 0, 0, 0);
    }
  }
  float ps[4] = {0.f, 0.f, 0.f, 0.f}, pd[4] = {0.f, 0.f, 0.f, 0.f};
#pragma unroll
  for (int nt = 0; nt < 4; ++nt) {
    const int coln = n0 + nt * 16 + t;
    const float a_s = asrc[coln], a_d = adst[coln];
#pragma unroll
    for (int r = 0; r < 4; ++r) {
      const float d = acc[nt][r];
      h[(size_t)(m0 + q * 4 + r) * 256 + coln] = f2bf(d);
      ps[r] += d * a_s;
      pd[r] += d * a_d;
    }
  }
#pragma unroll
  for (int off = 1; off < 16; off <<= 1)
#pragma unroll
    for (int r = 0; r < 4; ++r) {
      ps[r] += __shfl_xor(ps[r], off, 64);
      pd[r] += __shfl_xor(pd[r], off, 64);
    }
  if (t == 0) {
#pragma unroll
    for (int r = 0; r < 4; ++r) {
      const int row = m0 + q * 4 + r;
      as_[(size_t)row * 4 + wv] = ps[r];
      ad_[(size_t)row * 4 + wv] = pd[r];
    }
  }
}

// ---------------- agg layer 1: 2 half-waves per node (128 ch each) + BN stats ------
// block = 4 waves = 2 nodes x 2 halves; 8-deep gather unroll (VGPR 32, occ ~60%).
__global__ __launch_bounds__(256) void gat_agg1_k(const int* __restrict__ rowptr,
                                                  const int* __restrict__ col,
                                                  const u16* __restrict__ h,
                                                  const float* __restrict__ as_,
                                                  const float* __restrict__ ad_,
                                                  u16* __restrict__ out,
                                                  float* __restrict__ accp) {  // [NPART1][512]
  __shared__ int   s_s[4][64];
  __shared__ float s_w[4][64][2];
  __shared__ float st_s[2][256], st_q[2][256];
  const int tid = threadIdx.x;
  const int wv = tid >> 6, lane = tid & 63;
  const int nl = wv >> 1, half = wv & 1;
  const int n = blockIdx.x * 2 + nl;
  const int beg = rowptr[n], end = rowptr[n + 1];
  const int c0 = half * 128 + lane * 2;
  const int hl = lane >> 5;        // head-within-half for this lane
  const int hb = half * 2;         // this half-wave covers heads hb, hb+1
  const float adv0 = ad_[n * 4 + hb], adv1 = ad_[n * 4 + hb + 1];

  float a0 = 0.f, a1 = 0.f, smh = 0.f;

  for (int j0 = beg; j0 < end; j0 += 64) {
    const int cnt = min(64, end - j0);
    const int j = j0 + lane;
    const int sl = col[(j < end) ? j : beg];
    s_s[wv][lane] = sl;
    const float4 av = *(const float4*)(as_ + (size_t)sl * 4);
    const float* ap = (const float*)&av;
    float e0 = ap[hb] + adv0;     e0 = e0 > 0.f ? e0 : SLOPE * e0;
    float e1 = ap[hb + 1] + adv1; e1 = e1 > 0.f ? e1 : SLOPE * e1;
    s_w[wv][lane][0] = (j < end) ? __expf(e0) : 0.f;
    s_w[wv][lane][1] = (j < end) ? __expf(e1) : 0.f;
    // wave-synchronous LDS (same wave wrote it)

    int jj = 0;
    for (; jj + 8 <= cnt; jj += 8) {
      int sv[8]; float wt[8]; ushort2 g[8];
#pragma unroll
      for (int u = 0; u < 8; ++u) {
        sv[u] = s_s[wv][jj + u];
        wt[u] = s_w[wv][jj + u][hl];
      }
#pragma unroll
      for (int u = 0; u < 8; ++u) g[u] = *(const ushort2*)(h + (size_t)sv[u] * 256 + c0);
#pragma unroll
      for (int u = 0; u < 8; ++u) {
        smh += wt[u];
        a0 = fmaf(wt[u], bf2f(g[u].x), a0);
        a1 = fmaf(wt[u], bf2f(g[u].y), a1);
      }
    }
    for (; jj < cnt; ++jj) {
      const int s = s_s[wv][jj];
      const float w = s_w[wv][jj][hl];
      const ushort2 g = *(const ushort2*)(h + (size_t)s * 256 + c0);
      smh += w;
      a0 = fmaf(w, bf2f(g.x), a0);
      a1 = fmaf(w, bf2f(g.y), a1);
    }
  }

  const float r = 1.f / (smh + 1e-16f);
  const float v0 = a0 * r, v1 = a1 * r;
  ushort2 o; o.x = f2bf(v0); o.y = f2bf(v1);
  *(ushort2*)(out + (size_t)n * 256 + c0) = o;

  // BN1 stats: per-block reduce over 2 nodes, one atomic set per block
  st_s[nl][c0] = v0;      st_s[nl][c0 + 1] = v1;
  st_q[nl][c0] = v0 * v0; st_q[nl][c0 + 1] = v1 * v1;
  __syncthreads();
  {
    const int c = tid;   // 256 channels
    const float s = st_s[0][c] + st_s[1][c];
    const float q = st_q[0][c] + st_q[1][c];
    float* dst = accp + (size_t)(blockIdx.x & (NPART1 - 1)) * 512;
    atomicAdd(&dst[c], s);
    atomicAdd(&dst[256 + c], q);
  }
}

// ---------------- agg layer 2: 1 wave per node (V=2) + BN stats ----------------
__global__ __launch_bounds__(256) void gat_agg2_k(const int* __restrict__ rowptr,
                                                  const int* __restrict__ col,
                                                  const u16* __restrict__ h,
                                                  const float* __restrict__ as_,
                                                  const float* __restrict__ ad_,
                                                  u16* __restrict__ out,
                                                  float* __restrict__ accp) {  // [NPART2][256]
  __shared__ int   s_s[4][64];
  __shared__ float s_w[4][64];
  __shared__ float st_s[4][128], st_q[4][128];
  const int tid = threadIdx.x;
  const int wv = tid >> 6, lane = tid & 63;
  const int n = blockIdx.x * 4 + wv;
  const int beg = rowptr[n], end = rowptr[n + 1];
  const int c0 = lane * 2;
  const float adv = ad_[n];

  float a0 = 0.f, a1 = 0.f, smh = 0.f;

  for (int j0 = beg; j0 < end; j0 += 64) {
    const int cnt = min(64, end - j0);
    const int j = j0 + lane;
    const int sl = col[(j < end) ? j : beg];
    s_s[wv][lane] = sl;
    float e = as_[sl] + adv;
    e = e > 0.f ? e : SLOPE * e;
    s_w[wv][lane] = (j < end) ? __expf(e) : 0.f;

    int jj = 0;
    for (; jj + 8 <= cnt; jj += 8) {
      int sv[8]; float wt[8]; ushort2 g[8];
#pragma unroll
      for (int u = 0; u < 8; ++u) {
        sv[u] = s_s[wv][jj + u];
        wt[u] = s_w[wv][jj + u];
      }
#pragma unroll
      for (int u = 0; u < 8; ++u) g[u] = *(const ushort2*)(h + (size_t)sv[u] * 128 + c0);
#pragma unroll
      for (int u = 0; u < 8; ++u) {
        smh += wt[u];
        a0 = fmaf(wt[u], bf2f(g[u].x), a0);
        a1 = fmaf(wt[u], bf2f(g[u].y), a1);
      }
    }
    for (; jj < cnt; ++jj) {
      const int s = s_s[wv][jj];
      const float w = s_w[wv][jj];
      const ushort2 g = *(const ushort2*)(h + (size_t)s * 128 + c0);
      smh += w;
      a0 = fmaf(w, bf2f(g.x), a0);
      a1 = fmaf(w, bf2f(g.y), a1);
    }
  }

  const float r = 1.f / (smh + 1e-16f);
  const float v0 = a0 * r, v1 = a1 * r;
  ushort2 o; o.x = f2bf(v0); o.y = f2bf(v1);
  *(ushort2*)(out + (size_t)n * 128 + c0) = o;

  st_s[wv][c0] = v0;      st_s[wv][c0 + 1] = v1;
  st_q[wv][c0] = v0 * v0; st_q[wv][c0 + 1] = v1 * v1;
  __syncthreads();
  if (tid < 128) {
    const int c = tid;
    const float s = st_s[0][c] + st_s[1][c] + st_s[2][c] + st_s[3][c];
    const float q = st_q[0][c] + st_q[1][c] + st_q[2][c] + st_q[3][c];
    float* dst = accp + (size_t)(blockIdx.x & (NPART2 - 1)) * 256;
    atomicAdd(&dst[c], s);
    atomicAdd(&dst[128 + c], q);
  }
}

// ---------------- GEMM2 (MFMA) + BN1 finalize-from-partials + ELU on A + alpha2 ----
__global__ __launch_bounds__(256) void gemm2_mfma_k(const u16* __restrict__ hin,
                                                    const float* __restrict__ accp, // [NPART1][512]
                                                    const float* __restrict__ g1,
                                                    const float* __restrict__ b1,
                                                    const u16* __restrict__ wp,   // [128][256]
                                                    const float* __restrict__ asrc,
                                                    const float* __restrict__ adst,
                                                    u16* __restrict__ h2,
                                                    float* __restrict__ as_,
                                                    float* __restrict__ ad_) {
  __shared__ float scsh[512];
  __shared__ float red[2][32][2];
  const int tid = threadIdx.x;
  {  // BN1 finalize: sum NPART1 partials per channel
    float s = 0.f, q = 0.f;
#pragma unroll
    for (int p = 0; p < NPART1; ++p) {
      s += accp[(size_t)p * 512 + tid];
      q += accp[(size_t)p * 512 + 256 + tid];
    }
    const float mean = s * (1.f / N_N);
    const float var  = q * (1.f / N_N) - mean * mean;
    const float inv  = rsqrtf(var + BNEPS);
    const float sc   = g1[tid] * inv;
    scsh[tid]       = sc;
    scsh[256 + tid] = b1[tid] - mean * sc;
  }
  __syncthreads();
  const int wv = tid >> 6, lane = tid & 63;
  const int q = lane >> 4, t = lane & 15;
  const int mh = wv >> 1, nh = wv & 1;
  const int m0 = blockIdx.x * 32 + mh * 16;
  const int n0 = nh * 64;
  f32x4 acc[4] = {};
#pragma unroll
  for (int kb = 0; kb < 8; ++kb) {
    const int k0 = kb * 32 + q * 8;
    const ushort4 u0 = *(const ushort4*)(hin + (size_t)(m0 + t) * 256 + k0);
    const ushort4 u1 = *(const ushort4*)(hin + (size_t)(m0 + t) * 256 + k0 + 4);
    const float4 sc0 = *(const float4*)(scsh + k0);
    const float4 sc1 = *(const float4*)(scsh + k0 + 4);
    const float4 sh0 = *(const float4*)(scsh + 256 + k0);
    const float4 sh1 = *(const float4*)(scsh + 256 + k0 + 4);
    float v[8];
    v[0] = bf2f(u0.x) * sc0.x + sh0.x;
    v[1] = bf2f(u0.y) * sc0.y + sh0.y;
    v[2] = bf2f(u0.z) * sc0.z + sh0.z;
    v[3] = bf2f(u0.w) * sc0.w + sh0.w;
    v[4] = bf2f(u1.x) * sc1.x + sh1.x;
    v[5] = bf2f(u1.y) * sc1.y + sh1.y;
    v[6] = bf2f(u1.z) * sc1.z + sh1.z;
    v[7] = bf2f(u1.w) * sc1.w + sh1.w;
    bf16x8 a;
#pragma unroll
    for (int j = 0; j < 8; ++j) {
      const float e = v[j] > 0.f ? v[j] : __expf(v[j]) - 1.f;
      a[j] = (short)f2bf(e);
    }
#pragma unroll
    for (int nt = 0; nt < 4; ++nt) {
      const int n = n0 + nt * 16 + t;
      const bf16x8 b = *(const bf16x8*)(wp + (size_t)n * 256 + k0);
      acc[nt] = __builtin_amdgcn_mfma_f32_16x16x32_bf16(a, b, acc[nt], 0, 0, 0);
    }
  }
  float ps[4] = {0.f, 0.f, 0.f, 0.f}, pd[4] = {0.f, 0.f, 0.f, 0.f};
#pragma unroll
  for (int nt = 0; nt < 4; ++nt) {
    const int coln = n0 + nt * 16 + t;
    const float a_s = asrc[coln], a_d = adst[coln];
#pragma unroll
    for (int r = 0; r < 4; ++r) {
      const float d = acc[nt][r];
      h2[(size_t)(m0 + q * 4 + r) * 128 + coln] = f2bf(d);
      ps[r] += d * a_s;
      pd[r] += d * a_d;
    }
  }
#pragma unroll
  for (int off = 1; off < 16; off <<= 1)
#pragma unroll
    for (int r = 0; r < 4; ++r) {
      ps[r] += __shfl_xor(ps[r], off, 64);
      pd[r] += __shfl_xor(pd[r], off, 64);
    }
  if (t == 0) {
#pragma unroll
    for (int r = 0; r < 4; ++r) {
      red[0][mh * 16 + q * 4 + r][nh] = ps[r];
      red[1][mh * 16 + q * 4 + r][nh] = pd[r];
    }
  }
  __syncthreads();
  if (tid < 32) {
    as_[(size_t)blockIdx.x * 32 + tid] = red[0][tid][0] + red[0][tid][1];
    ad_[(size_t)blockIdx.x * 32 + tid] = red[1][tid][0] + red[1][tid][1];
  }
}

// ---------------- BN2 finalize-from-partials + apply, bf16 -> fp32 out -------------
__global__ __launch_bounds__(256) void apply_k(const u16* __restrict__ X,
                                               const float* __restrict__ accp, // [NPART2][256]
                                               const float* __restrict__ gamma,
                                               const float* __restrict__ beta,
                                               float* __restrict__ Y) {
  __shared__ float s_sc[128], s_sh[128];
  const int tid = threadIdx.x;
  if (tid < 128) {
    float s = 0.f, q = 0.f;
#pragma unroll
    for (int p = 0; p < NPART2; ++p) {
      s += accp[(size_t)p * 256 + tid];
      q += accp[(size_t)p * 256 + 128 + tid];
    }
    const float mean = s * (1.f / N_N);
    const float var  = q * (1.f / N_N) - mean * mean;
    const float inv  = rsqrtf(var + BNEPS);
    const float sc   = gamma[tid] * inv;
    s_sc[tid] = sc;
    s_sh[tid] = beta[tid] - mean * sc;
  }
  __syncthreads();
  constexpr size_t TOT = (size_t)N_N * OUTD;
  for (size_t i = ((size_t)blockIdx.x * 256 + tid) * 4; i < TOT;
       i += (size_t)gridDim.x * 256 * 4) {
    const ushort4 u = *(const ushort4*)(X + i);
    const int c = (int)(i & 127);
    float4 o;
    o.x = bf2f(u.x) * s_sc[c]     + s_sh[c];
    o.y = bf2f(u.y) * s_sc[c + 1] + s_sh[c + 1];
    o.z = bf2f(u.z) * s_sc[c + 2] + s_sh[c + 2];
    o.w = bf2f(u.w) * s_sc[c + 3] + s_sh[c + 3];
    *(float4*)(Y + i) = o;
  }
}

// ---------------- workspace layout (4-byte element offsets) ----------------
constexpr size_t OFF_WP1  = 0;                                   // bf16 256*128
constexpr size_t OFF_WP2  = OFF_WP1  + (size_t)IN_D * HID / 2;
constexpr size_t OFF_H1   = OFF_WP2  + (size_t)HID * OUTD / 2;   // bf16 N_N*HID
constexpr size_t OFF_OUT1 = OFF_H1   + (size_t)N_N * HID / 2;
constexpr size_t OFF_H2   = OFF_OUT1 + (size_t)N_N * HID / 2;    // bf16 N_N*OUTD
constexpr size_t OFF_OUT2 = OFF_H2   + (size_t)N_N * OUTD / 2;
constexpr size_t OFF_AS1  = OFF_OUT2 + (size_t)N_N * OUTD / 2;   // fp32 N_N*4
constexpr size_t OFF_AD1  = OFF_AS1  + (size_t)N_N * H1;
constexpr size_t OFF_AS2  = OFF_AD1  + (size_t)N_N * H1;         // fp32 N_N
constexpr size_t OFF_AD2  = OFF_AS2  + (size_t)N_N;
constexpr size_t OFF_ROWP = OFF_AD2  + (size_t)N_N;              // int N_N+1
constexpr size_t OFF_COL  = OFF_ROWP + (size_t)(N_N + 1);        // int N_ET
constexpr size_t OFF_WCUR = OFF_COL  + (size_t)N_ET;             // int N_N
// zeroed region (one memset): cnt + acc partials
constexpr size_t OFF_CNT  = OFF_WCUR + (size_t)N_N;              // int N_N
constexpr size_t OFF_ACC1 = OFF_CNT  + (size_t)N_N;              // NPART1*512 fp32
constexpr size_t OFF_ACC2 = OFF_ACC1 + (size_t)NPART1 * 512;     // NPART2*256 fp32
constexpr size_t OFF_ZEND = OFF_ACC2 + (size_t)NPART2 * 256;

extern "C" void kernel_launch(void* const* d_in, const int* in_sizes, int n_in,
                              void* d_out, int out_size, void* d_ws, size_t ws_size,
                              hipStream_t stream) {
  const float* x      = (const float*)d_in[0];
  const int*   ei     = (const int*)d_in[1];
  const float* W1     = (const float*)d_in[2];
  const float* asrc1  = (const float*)d_in[3];
  const float* adst1  = (const float*)d_in[4];
  // d_in[5] = bias1 (cancels under BN)
  const float* g1     = (const float*)d_in[6];
  const float* b1     = (const float*)d_in[7];
  const float* W2     = (const float*)d_in[8];
  const float* asrc2  = (const float*)d_in[9];
  const float* adst2  = (const float*)d_in[10];
  // d_in[11] = bias2 (cancels under BN)
  const float* g2     = (const float*)d_in[12];
  const float* b2     = (const float*)d_in[13];

  float* ws = (float*)d_ws;
  u16*   wp1   = (u16*)(ws + OFF_WP1);
  u16*   wp2   = (u16*)(ws + OFF_WP2);
  u16*   h1    = (u16*)(ws + OFF_H1);
  u16*   out1  = (u16*)(ws + OFF_OUT1);
  u16*   h2    = (u16*)(ws + OFF_H2);
  u16*   out2  = (u16*)(ws + OFF_OUT2);
  float* as1   = ws + OFF_AS1;
  float* ad1   = ws + OFF_AD1;
  float* as2   = ws + OFF_AS2;
  float* ad2   = ws + OFF_AD2;
  int*   rowp  = (int*)(ws + OFF_ROWP);
  int*   col   = (int*)(ws + OFF_COL);
  int*   wcur  = (int*)(ws + OFF_WCUR);
  int*   cnt   = (int*)(ws + OFF_CNT);
  float* acc1p = ws + OFF_ACC1;
  float* acc2p = ws + OFF_ACC2;
  float* outf  = (float*)d_out;

  // zero: cnt + acc partials (contiguous, ~240 KB)
  hipMemsetAsync(cnt, 0, (OFF_ZEND - OFF_CNT) * sizeof(float), stream);

  const int eb = (N_ET + 255) / 256;   // 1329
  // 1. W packs + degree histogram
  prep_k<<<eb, 256, 0, stream>>>(ei, W1, W2, wp1, wp2, cnt);
  // 2. exclusive scan -> rowptr/wcur
  scan_k<<<1, 1024, 0, stream>>>(cnt, rowp, wcur);
  // 3. CSR scatter + GEMM1(+alpha1) fused
  sg_k<<<GB1 + eb, 256, 0, stream>>>(x, wp1, asrc1, adst1, h1, as1, ad1, ei, wcur, col);
  // 4. layer-1 edge softmax + aggregate + BN1 stats partials
  gat_agg1_k<<<N_N / 2, 256, 0, stream>>>(rowp, col, h1, as1, ad1, out1, acc1p);
  // 5. GEMM2 (BN1 finalize + BN1/ELU on A, fused alpha2)
  gemm2_mfma_k<<<N_N / 32, 256, 0, stream>>>(out1, acc1p, g1, b1, wp2, asrc2, adst2, h2, as2, ad2);
  // 6. layer-2 edge softmax + aggregate + BN2 stats partials
  gat_agg2_k<<<N_N / 4, 256, 0, stream>>>(rowp, col, h2, as2, ad2, out2, acc2p);
  // 7. BN2 finalize + apply -> fp32 output
  apply_k<<<512, 256, 0, stream>>>(out2, acc2p, g2, b2, outf);
}